// Round 1
// baseline (628.719 us; speedup 1.0000x reference)
//
#include <hip/hip_runtime.h>

#define N_NODESC 100000
#define N_EDGESC 10000
#define N_PAIRSC 1600000
#define FDIM 128
#define NCH_E 40     // ceil(10000/256)
#define NCH_N 391    // ceil(100000/256)

typedef short bf16x8 __attribute__((ext_vector_type(8)));
typedef float f32x4 __attribute__((ext_vector_type(4)));

__device__ __forceinline__ unsigned short f2b(float f) {
  unsigned u = __float_as_uint(f);
  u += 0x7fffu + ((u >> 16) & 1u);
  return (unsigned short)(u >> 16);
}
__device__ __forceinline__ float b2f(unsigned short b) {
  return __uint_as_float(((unsigned)b) << 16);
}
__device__ __forceinline__ unsigned pack2(float a, float b) {
  return (unsigned)f2b(a) | ((unsigned)f2b(b) << 16);
}
__device__ __forceinline__ float gelu_exact(float z) {
  return 0.5f * z * (1.0f + erff(z * 0.70710678118f));
}

// ---------------- zero counters ----------------
__global__ __launch_bounds__(256) void k_zero(int* ecnt, int* ncnt) {
  int i = blockIdx.x * 256 + threadIdx.x;
  if (i < N_EDGESC) ecnt[i] = 0;
  if (i < N_NODESC) ncnt[i] = 0;
}

// ---------------- prep: bf16 convert + send/recv + histograms ----------------
__global__ __launch_bounds__(256) void k_prep(const float* __restrict__ x, const float* __restrict__ action,
                                              const float* __restrict__ wmsg, const float* __restrict__ wupd,
                                              const int* __restrict__ pn, const int* __restrict__ pe,
                                              short* __restrict__ xb, short* __restrict__ wmsgb,
                                              short* __restrict__ wupdb, float* __restrict__ send,
                                              float* __restrict__ recv, int* __restrict__ ecnt,
                                              int* __restrict__ ncnt) {
  int i = blockIdx.x * 256 + threadIdx.x;
  if (i < (N_NODESC * FDIM) / 4) {
    const float4 v = ((const float4*)x)[i];
    uint2 o;
    o.x = pack2(v.x, v.y);
    o.y = pack2(v.z, v.w);
    ((uint2*)xb)[i] = o;
  }
  if (i < FDIM * FDIM) {
    wmsgb[i] = (short)f2b(wmsg[i]);
    wupdb[i] = (short)f2b(wupd[i]);
  }
  if (i < N_NODESC) {
    float a0 = action[i * 3 + 0], a1 = action[i * 3 + 1], a2 = action[i * 3 + 2];
    send[i] = a0 + a2;
    recv[i] = a0 + a1;
  }
  if (i < N_PAIRSC) {
    atomicAdd(&ecnt[pe[i]], 1);
    atomicAdd(&ncnt[pn[i]], 1);
  }
}

// ---------------- scan helpers ----------------
__device__ __forceinline__ int wave_incl_scan(int v, int lane) {
#pragma unroll
  for (int d = 1; d < 64; d <<= 1) {
    int n = __shfl_up(v, d, 64);
    if (lane >= d) v += n;
  }
  return v;
}

// P1: per-256-chunk sums. blocks [0,NCH_E) -> edge, [NCH_E, NCH_E+NCH_N) -> node
__global__ __launch_bounds__(256) void k_chunksum(const int* __restrict__ ecnt, const int* __restrict__ ncnt,
                                                  int* __restrict__ csum) {
  int b = blockIdx.x, t = threadIdx.x, lane = t & 63, w = t >> 6;
  int v;
  if (b < NCH_E) {
    int i = b * 256 + t;
    v = (i < N_EDGESC) ? ecnt[i] : 0;
  } else {
    int i = (b - NCH_E) * 256 + t;
    v = (i < N_NODESC) ? ncnt[i] : 0;
  }
#pragma unroll
  for (int d = 32; d; d >>= 1) v += __shfl_down(v, d, 64);
  __shared__ int wsum[4];
  if (lane == 0) wsum[w] = v;
  __syncthreads();
  if (t == 0) csum[b] = wsum[0] + wsum[1] + wsum[2] + wsum[3];
}

// P2: exclusive-scan the chunk sums (two independent segments), single wave
__global__ void k_scanchunks(int* __restrict__ csum) {
  int lane = threadIdx.x;
  int carry = 0;
  for (int base = 0; base < NCH_E; base += 64) {
    int idx = base + lane;
    int v = (idx < NCH_E) ? csum[idx] : 0;
    int inc = wave_incl_scan(v, lane);
    if (idx < NCH_E) csum[idx] = carry + inc - v;
    carry += __shfl(inc, 63, 64);
  }
  carry = 0;
  for (int base = 0; base < NCH_N; base += 64) {
    int idx = base + lane;
    int v = (idx < NCH_N) ? csum[NCH_E + idx] : 0;
    int inc = wave_incl_scan(v, lane);
    if (idx < NCH_N) csum[NCH_E + idx] = carry + inc - v;
    carry += __shfl(inc, 63, 64);
  }
}

// P3: block-local exclusive scan + chunk base -> offsets & cursors
__global__ __launch_bounds__(256) void k_offsets(const int* __restrict__ ecnt, const int* __restrict__ ncnt,
                                                 const int* __restrict__ csum, int* __restrict__ eoff,
                                                 int* __restrict__ ecur, int* __restrict__ noff,
                                                 int* __restrict__ ncur) {
  int b = blockIdx.x, t = threadIdx.x, lane = t & 63, w = t >> 6;
  const int* cnt;
  int* off;
  int* cur;
  int i, n;
  if (b < NCH_E) {
    i = b * 256 + t; n = N_EDGESC; cnt = ecnt; off = eoff; cur = ecur;
  } else {
    i = (b - NCH_E) * 256 + t; n = N_NODESC; cnt = ncnt; off = noff; cur = ncur;
  }
  int base = csum[b];
  int v = (i < n) ? cnt[i] : 0;
  int inc = wave_incl_scan(v, lane);
  __shared__ int wsum[4], woff[4];
  if (lane == 63) wsum[w] = inc;
  __syncthreads();
  if (t == 0) {
    int s = 0;
#pragma unroll
    for (int k = 0; k < 4; k++) { woff[k] = s; s += wsum[k]; }
  }
  __syncthreads();
  int excl = base + woff[w] + inc - v;
  if (i < n) { off[i] = excl; cur[i] = excl; }
}

// ---------------- scatter into sorted order ----------------
__global__ __launch_bounds__(256) void k_scatter(const int* __restrict__ pn, const int* __restrict__ pe,
                                                 int* __restrict__ ecur, int* __restrict__ ncur,
                                                 int* __restrict__ sn, int* __restrict__ se) {
  int i = blockIdx.x * 256 + threadIdx.x;
  if (i >= N_PAIRSC) return;
  int v = pn[i], e = pe[i];
  int pos = atomicAdd(&ecur[e], 1);
  sn[pos] = v;
  int pos2 = atomicAdd(&ncur[v], 1);
  se[pos2] = e;
}

// ---------------- GEMM 1: m_ji = gelu(x @ Wmsg^T) * send  -> bf16 ----------------
__global__ __launch_bounds__(256) void k_gemm_msg(const short* __restrict__ xb, const short* __restrict__ wb,
                                                  const float* __restrict__ send, short* __restrict__ mji) {
  int gw = (blockIdx.x * 256 + threadIdx.x) >> 6;
  int lane = threadIdx.x & 63;
  int rb = gw * 16;
  if (rb >= N_NODESC) return;
  int lr = lane & 15, lg = lane >> 4;

  bf16x8 A[4];
  const short* xrow = xb + (size_t)(rb + lr) * FDIM + lg * 8;
#pragma unroll
  for (int kk = 0; kk < 4; kk++) A[kk] = *(const bf16x8*)(xrow + kk * 32);

  float sv[4];
#pragma unroll
  for (int j = 0; j < 4; j++) sv[j] = send[rb + lg * 4 + j];

#pragma unroll
  for (int c = 0; c < 8; c++) {
    f32x4 acc = {0.f, 0.f, 0.f, 0.f};
    const short* wrow = wb + (size_t)(16 * c + lr) * FDIM + lg * 8;
#pragma unroll
    for (int kk = 0; kk < 4; kk++) {
      bf16x8 B = *(const bf16x8*)(wrow + kk * 32);
      acc = __builtin_amdgcn_mfma_f32_16x16x32_bf16(A[kk], B, acc, 0, 0, 0);
    }
#pragma unroll
    for (int j = 0; j < 4; j++) {
      float z = acc[j];
      float m = gelu_exact(z) * sv[j];
      int row = rb + lg * 4 + j, col = 16 * c + lr;
      mji[(size_t)row * FDIM + col] = (short)f2b(m);
    }
  }
}

// ---------------- edge reduce: e_feat = mean over pairs of m_ji[node] ----------------
__global__ __launch_bounds__(256) void k_edge(const short* __restrict__ mji, const int* __restrict__ sn,
                                              const int* __restrict__ eoff, const int* __restrict__ ecnt,
                                              short* __restrict__ efeat) {
  int wv = blockIdx.x * 4 + (threadIdx.x >> 6);
  int lane = threadIdx.x & 63;
  if (wv >= N_EDGESC) return;
  int beg = eoff[wv], cnt = ecnt[wv];
  float a0 = 0.f, a1 = 0.f;
#pragma unroll 4
  for (int p = 0; p < cnt; p++) {
    int node = sn[beg + p];
    unsigned u = *(const unsigned*)(mji + (size_t)node * FDIM + lane * 2);
    a0 += __uint_as_float(u << 16);
    a1 += __uint_as_float(u & 0xffff0000u);
  }
  float inv = 1.0f / fmaxf((float)cnt, 1.0f);
  ((unsigned*)(efeat + (size_t)wv * FDIM))[lane] = pack2(a0 * inv, a1 * inv);
}

// ---------------- node reduce: m_i = recv/deg * sum over pairs of e_feat[edge] ----------------
__global__ __launch_bounds__(256) void k_node(const short* __restrict__ efeat, const int* __restrict__ se,
                                              const int* __restrict__ noff, const int* __restrict__ ncnt,
                                              const float* __restrict__ recv, short* __restrict__ mi) {
  int wv = blockIdx.x * 4 + (threadIdx.x >> 6);
  int lane = threadIdx.x & 63;
  if (wv >= N_NODESC) return;
  int beg = noff[wv], cnt = ncnt[wv];
  float a0 = 0.f, a1 = 0.f;
#pragma unroll 4
  for (int p = 0; p < cnt; p++) {
    int e = se[beg + p];
    unsigned u = *(const unsigned*)(efeat + (size_t)e * FDIM + lane * 2);
    a0 += __uint_as_float(u << 16);
    a1 += __uint_as_float(u & 0xffff0000u);
  }
  float s = recv[wv] / fmaxf((float)cnt, 1.0f);
  ((unsigned*)(mi + (size_t)wv * FDIM))[lane] = pack2(a0 * s, a1 * s);
}

// ---------------- GEMM 2: out = gelu(x @ Wupd^T + b + m_i)  -> f32 ----------------
__global__ __launch_bounds__(256) void k_gemm_upd(const short* __restrict__ xb, const short* __restrict__ wb,
                                                  const float* __restrict__ bias, const short* __restrict__ mi,
                                                  float* __restrict__ out) {
  int gw = (blockIdx.x * 256 + threadIdx.x) >> 6;
  int lane = threadIdx.x & 63;
  int rb = gw * 16;
  if (rb >= N_NODESC) return;
  int lr = lane & 15, lg = lane >> 4;

  bf16x8 A[4];
  const short* xrow = xb + (size_t)(rb + lr) * FDIM + lg * 8;
#pragma unroll
  for (int kk = 0; kk < 4; kk++) A[kk] = *(const bf16x8*)(xrow + kk * 32);

#pragma unroll
  for (int c = 0; c < 8; c++) {
    f32x4 acc = {0.f, 0.f, 0.f, 0.f};
    const short* wrow = wb + (size_t)(16 * c + lr) * FDIM + lg * 8;
#pragma unroll
    for (int kk = 0; kk < 4; kk++) {
      bf16x8 B = *(const bf16x8*)(wrow + kk * 32);
      acc = __builtin_amdgcn_mfma_f32_16x16x32_bf16(A[kk], B, acc, 0, 0, 0);
    }
    int col = 16 * c + lr;
    float bc = bias[col];
#pragma unroll
    for (int j = 0; j < 4; j++) {
      int row = rb + lg * 4 + j;
      float z = acc[j] + bc + b2f(((const unsigned short*)mi)[(size_t)row * FDIM + col]);
      out[(size_t)row * FDIM + col] = gelu_exact(z);
    }
  }
}

extern "C" void kernel_launch(void* const* d_in, const int* in_sizes, int n_in,
                              void* d_out, int out_size, void* d_ws, size_t ws_size,
                              hipStream_t stream) {
  const float* x = (const float*)d_in[0];
  const float* action = (const float*)d_in[1];
  const float* wmsg = (const float*)d_in[2];
  const float* wupd = (const float*)d_in[3];
  const float* bupd = (const float*)d_in[4];
  const int* pn = (const int*)d_in[5];
  const int* pe = (const int*)d_in[6];
  float* out = (float*)d_out;

  char* p = (char*)d_ws;
  auto alloc = [&](size_t bytes) -> char* {
    char* r = p;
    p += (bytes + 255) & ~(size_t)255;
    return r;
  };
  short* xb = (short*)alloc((size_t)N_NODESC * FDIM * 2);
  short* mji = (short*)alloc((size_t)N_NODESC * FDIM * 2);
  short* mi = (short*)alloc((size_t)N_NODESC * FDIM * 2);
  short* efeat = (short*)alloc((size_t)N_EDGESC * FDIM * 2);
  int* sn = (int*)alloc((size_t)N_PAIRSC * 4);
  int* se = (int*)alloc((size_t)N_PAIRSC * 4);
  short* wmsgb = (short*)alloc(FDIM * FDIM * 2);
  short* wupdb = (short*)alloc(FDIM * FDIM * 2);
  float* send = (float*)alloc(N_NODESC * 4);
  float* recv = (float*)alloc(N_NODESC * 4);
  int* ecnt = (int*)alloc(N_EDGESC * 4);
  int* eoff = (int*)alloc(N_EDGESC * 4);
  int* ecur = (int*)alloc(N_EDGESC * 4);
  int* ncnt = (int*)alloc(N_NODESC * 4);
  int* noff = (int*)alloc(N_NODESC * 4);
  int* ncur = (int*)alloc(N_NODESC * 4);
  int* csum = (int*)alloc((NCH_E + NCH_N) * 4);

  k_zero<<<(N_NODESC + 255) / 256, 256, 0, stream>>>(ecnt, ncnt);
  k_prep<<<12500, 256, 0, stream>>>(x, action, wmsg, wupd, pn, pe, xb, wmsgb, wupdb, send, recv, ecnt, ncnt);
  k_chunksum<<<NCH_E + NCH_N, 256, 0, stream>>>(ecnt, ncnt, csum);
  k_scanchunks<<<1, 64, 0, stream>>>(csum);
  k_offsets<<<NCH_E + NCH_N, 256, 0, stream>>>(ecnt, ncnt, csum, eoff, ecur, noff, ncur);
  k_scatter<<<(N_PAIRSC + 255) / 256, 256, 0, stream>>>(pn, pe, ecur, ncur, sn, se);
  k_gemm_msg<<<1563, 256, 0, stream>>>(xb, wmsgb, send, mji);
  k_edge<<<2500, 256, 0, stream>>>(mji, sn, eoff, ecnt, efeat);
  k_node<<<25000, 256, 0, stream>>>(efeat, se, noff, ncnt, recv, mi);
  k_gemm_upd<<<1563, 256, 0, stream>>>(xb, wupdb, bupd, mi, out);
}

// Round 3
// 548.481 us; speedup vs baseline: 1.1463x; 1.1463x over previous
//
#include <hip/hip_runtime.h>

#define N_NODESC 100000
#define N_EDGESC 10000
#define N_PAIRSC 1600000
#define FDIM 128
#define NCH_E 40     // ceil(10000/256)
#define NCH_N 391    // ceil(100000/256)

#define SC_CHUNK 2048
#define SC_NCHUNK ((N_PAIRSC + SC_CHUNK - 1) / SC_CHUNK)  // 782

typedef short bf16x8 __attribute__((ext_vector_type(8)));
typedef float f32x4 __attribute__((ext_vector_type(4)));
typedef int i32x4 __attribute__((ext_vector_type(4)));

__device__ __forceinline__ unsigned short f2b(float f) {
  unsigned u = __float_as_uint(f);
  u += 0x7fffu + ((u >> 16) & 1u);
  return (unsigned short)(u >> 16);
}
__device__ __forceinline__ float b2f(unsigned short b) {
  return __uint_as_float(((unsigned)b) << 16);
}
__device__ __forceinline__ unsigned pack2(float a, float b) {
  return (unsigned)f2b(a) | ((unsigned)f2b(b) << 16);
}
__device__ __forceinline__ float gelu_exact(float z) {
  return 0.5f * z * (1.0f + erff(z * 0.70710678118f));
}

// ---------------- zero counters ----------------
__global__ __launch_bounds__(256) void k_zero(int* ecnt, int* ncnt) {
  int i = blockIdx.x * 256 + threadIdx.x;
  if (i < N_EDGESC) ecnt[i] = 0;
  if (i < N_NODESC) ncnt[i] = 0;
}

// ---------------- prep: bf16 convert + send/recv + histograms ----------------
__global__ __launch_bounds__(256) void k_prep(const float* __restrict__ x, const float* __restrict__ action,
                                              const float* __restrict__ wmsg, const float* __restrict__ wupd,
                                              const int* __restrict__ pn, const int* __restrict__ pe,
                                              short* __restrict__ xb, short* __restrict__ wmsgb,
                                              short* __restrict__ wupdb, float* __restrict__ send,
                                              float* __restrict__ recv, int* __restrict__ ecnt,
                                              int* __restrict__ ncnt) {
  int i = blockIdx.x * 256 + threadIdx.x;
  if (i < (N_NODESC * FDIM) / 4) {
    const float4 v = ((const float4*)x)[i];
    uint2 o;
    o.x = pack2(v.x, v.y);
    o.y = pack2(v.z, v.w);
    ((uint2*)xb)[i] = o;
  }
  if (i < FDIM * FDIM) {
    wmsgb[i] = (short)f2b(wmsg[i]);
    wupdb[i] = (short)f2b(wupd[i]);
  }
  if (i < N_NODESC) {
    float a0 = action[i * 3 + 0], a1 = action[i * 3 + 1], a2 = action[i * 3 + 2];
    send[i] = a0 + a2;
    recv[i] = a0 + a1;
  }
  if (i < N_PAIRSC) {
    atomicAdd(&ecnt[pe[i]], 1);
    atomicAdd(&ncnt[pn[i]], 1);
  }
}

// ---------------- scan helpers ----------------
__device__ __forceinline__ int wave_incl_scan(int v, int lane) {
#pragma unroll
  for (int d = 1; d < 64; d <<= 1) {
    int n = __shfl_up(v, d, 64);
    if (lane >= d) v += n;
  }
  return v;
}

// P1: per-256-chunk sums. blocks [0,NCH_E) -> edge, [NCH_E, NCH_E+NCH_N) -> node
__global__ __launch_bounds__(256) void k_chunksum(const int* __restrict__ ecnt, const int* __restrict__ ncnt,
                                                  int* __restrict__ csum) {
  int b = blockIdx.x, t = threadIdx.x, lane = t & 63, w = t >> 6;
  int v;
  if (b < NCH_E) {
    int i = b * 256 + t;
    v = (i < N_EDGESC) ? ecnt[i] : 0;
  } else {
    int i = (b - NCH_E) * 256 + t;
    v = (i < N_NODESC) ? ncnt[i] : 0;
  }
#pragma unroll
  for (int d = 32; d; d >>= 1) v += __shfl_down(v, d, 64);
  __shared__ int wsum[4];
  if (lane == 0) wsum[w] = v;
  __syncthreads();
  if (t == 0) csum[b] = wsum[0] + wsum[1] + wsum[2] + wsum[3];
}

// P2: exclusive-scan the chunk sums (two independent segments), single wave
__global__ void k_scanchunks(int* __restrict__ csum) {
  int lane = threadIdx.x;
  int carry = 0;
  for (int base = 0; base < NCH_E; base += 64) {
    int idx = base + lane;
    int v = (idx < NCH_E) ? csum[idx] : 0;
    int inc = wave_incl_scan(v, lane);
    if (idx < NCH_E) csum[idx] = carry + inc - v;
    carry += __shfl(inc, 63, 64);
  }
  carry = 0;
  for (int base = 0; base < NCH_N; base += 64) {
    int idx = base + lane;
    int v = (idx < NCH_N) ? csum[NCH_E + idx] : 0;
    int inc = wave_incl_scan(v, lane);
    if (idx < NCH_N) csum[NCH_E + idx] = carry + inc - v;
    carry += __shfl(inc, 63, 64);
  }
}

// P3: block-local exclusive scan + chunk base -> offsets & cursors
__global__ __launch_bounds__(256) void k_offsets(const int* __restrict__ ecnt, const int* __restrict__ ncnt,
                                                 const int* __restrict__ csum, int* __restrict__ eoff,
                                                 int* __restrict__ ecur, int* __restrict__ noff,
                                                 int* __restrict__ ncur) {
  int b = blockIdx.x, t = threadIdx.x, lane = t & 63, w = t >> 6;
  const int* cnt;
  int* off;
  int* cur;
  int i, n;
  if (b < NCH_E) {
    i = b * 256 + t; n = N_EDGESC; cnt = ecnt; off = eoff; cur = ecur;
  } else {
    i = (b - NCH_E) * 256 + t; n = N_NODESC; cnt = ncnt; off = noff; cur = ncur;
  }
  int base = csum[b];
  int v = (i < n) ? cnt[i] : 0;
  int inc = wave_incl_scan(v, lane);
  __shared__ int wsum[4], woff[4];
  if (lane == 63) wsum[w] = inc;
  __syncthreads();
  if (t == 0) {
    int s = 0;
#pragma unroll
    for (int k = 0; k < 4; k++) { woff[k] = s; s += wsum[k]; }
  }
  __syncthreads();
  int excl = base + woff[w] + inc - v;
  if (i < n) { off[i] = excl; cur[i] = excl; }
}

// ---------------- scatter into sorted order, XCD-range partitioned ----------------
// blockIdx % 8 = range group r. Group r handles only edges in [r*1250,(r+1)*1250)
// and nodes in [r*12500,(r+1)*12500). With the round-robin block->XCD mapping all
// stores to a given sorted-output window come from one XCD, so cache lines fill
// completely in that L2 before writeback (vs 64B writeback per 4B store before).
// Correctness does NOT depend on the XCD mapping - only merge efficiency does.
__global__ __launch_bounds__(256) void k_scatter(const int* __restrict__ pn, const int* __restrict__ pe,
                                                 int* __restrict__ ecur, int* __restrict__ ncur,
                                                 int* __restrict__ sn, int* __restrict__ se) {
  int r = blockIdx.x & 7;
  int c = blockIdx.x >> 3;
  int base = c * SC_CHUNK;
  int elo = r * (N_EDGESC / 8), ehi = elo + (N_EDGESC / 8);
  int nlo = r * (N_NODESC / 8), nhi = nlo + (N_NODESC / 8);
#pragma unroll
  for (int k = 0; k < 2; k++) {
    int idx = base + k * 1024 + threadIdx.x * 4;
    if (idx >= N_PAIRSC) continue;
    i32x4 v4 = __builtin_nontemporal_load((const i32x4*)(pn + idx));
    i32x4 e4 = __builtin_nontemporal_load((const i32x4*)(pe + idx));
#pragma unroll
    for (int j = 0; j < 4; j++) {
      int vv = v4[j], ee = e4[j];
      if (ee >= elo && ee < ehi) {
        int pos = atomicAdd(&ecur[ee], 1);
        sn[pos] = vv;
      }
      if (vv >= nlo && vv < nhi) {
        int pos2 = atomicAdd(&ncur[vv], 1);
        se[pos2] = ee;
      }
    }
  }
}

// ---------------- GEMM 1: m_ji = gelu(x @ Wmsg^T) * send  -> bf16 ----------------
__global__ __launch_bounds__(256) void k_gemm_msg(const short* __restrict__ xb, const short* __restrict__ wb,
                                                  const float* __restrict__ send, short* __restrict__ mji) {
  int gw = (blockIdx.x * 256 + threadIdx.x) >> 6;
  int lane = threadIdx.x & 63;
  int rb = gw * 16;
  if (rb >= N_NODESC) return;
  int lr = lane & 15, lg = lane >> 4;

  bf16x8 A[4];
  const short* xrow = xb + (size_t)(rb + lr) * FDIM + lg * 8;
#pragma unroll
  for (int kk = 0; kk < 4; kk++) A[kk] = *(const bf16x8*)(xrow + kk * 32);

  float sv[4];
#pragma unroll
  for (int j = 0; j < 4; j++) sv[j] = send[rb + lg * 4 + j];

#pragma unroll
  for (int c = 0; c < 8; c++) {
    f32x4 acc = {0.f, 0.f, 0.f, 0.f};
    const short* wrow = wb + (size_t)(16 * c + lr) * FDIM + lg * 8;
#pragma unroll
    for (int kk = 0; kk < 4; kk++) {
      bf16x8 B = *(const bf16x8*)(wrow + kk * 32);
      acc = __builtin_amdgcn_mfma_f32_16x16x32_bf16(A[kk], B, acc, 0, 0, 0);
    }
#pragma unroll
    for (int j = 0; j < 4; j++) {
      float z = acc[j];
      float m = gelu_exact(z) * sv[j];
      int row = rb + lg * 4 + j, col = 16 * c + lr;
      mji[(size_t)row * FDIM + col] = (short)f2b(m);
    }
  }
}

// ---------------- edge reduce: e_feat = mean over pairs of m_ji[node] ----------------
__global__ __launch_bounds__(256) void k_edge(const short* __restrict__ mji, const int* __restrict__ sn,
                                              const int* __restrict__ eoff, const int* __restrict__ ecnt,
                                              short* __restrict__ efeat) {
  int wv = blockIdx.x * 4 + (threadIdx.x >> 6);
  int lane = threadIdx.x & 63;
  if (wv >= N_EDGESC) return;
  int beg = eoff[wv], cnt = ecnt[wv];
  float a0 = 0.f, a1 = 0.f;
#pragma unroll 4
  for (int p = 0; p < cnt; p++) {
    int node = sn[beg + p];
    unsigned u = *(const unsigned*)(mji + (size_t)node * FDIM + lane * 2);
    a0 += __uint_as_float(u << 16);
    a1 += __uint_as_float(u & 0xffff0000u);
  }
  float inv = 1.0f / fmaxf((float)cnt, 1.0f);
  ((unsigned*)(efeat + (size_t)wv * FDIM))[lane] = pack2(a0 * inv, a1 * inv);
}

// ---------------- node reduce: m_i = recv/deg * sum over pairs of e_feat[edge] ----------------
__global__ __launch_bounds__(256) void k_node(const short* __restrict__ efeat, const int* __restrict__ se,
                                              const int* __restrict__ noff, const int* __restrict__ ncnt,
                                              const float* __restrict__ recv, short* __restrict__ mi) {
  int wv = blockIdx.x * 4 + (threadIdx.x >> 6);
  int lane = threadIdx.x & 63;
  if (wv >= N_NODESC) return;
  int beg = noff[wv], cnt = ncnt[wv];
  float a0 = 0.f, a1 = 0.f;
#pragma unroll 4
  for (int p = 0; p < cnt; p++) {
    int e = se[beg + p];
    unsigned u = *(const unsigned*)(efeat + (size_t)e * FDIM + lane * 2);
    a0 += __uint_as_float(u << 16);
    a1 += __uint_as_float(u & 0xffff0000u);
  }
  float s = recv[wv] / fmaxf((float)cnt, 1.0f);
  ((unsigned*)(mi + (size_t)wv * FDIM))[lane] = pack2(a0 * s, a1 * s);
}

// ---------------- GEMM 2: out = gelu(x @ Wupd^T + b + m_i)  -> f32 ----------------
__global__ __launch_bounds__(256) void k_gemm_upd(const short* __restrict__ xb, const short* __restrict__ wb,
                                                  const float* __restrict__ bias, const short* __restrict__ mi,
                                                  float* __restrict__ out) {
  int gw = (blockIdx.x * 256 + threadIdx.x) >> 6;
  int lane = threadIdx.x & 63;
  int rb = gw * 16;
  if (rb >= N_NODESC) return;
  int lr = lane & 15, lg = lane >> 4;

  bf16x8 A[4];
  const short* xrow = xb + (size_t)(rb + lr) * FDIM + lg * 8;
#pragma unroll
  for (int kk = 0; kk < 4; kk++) A[kk] = *(const bf16x8*)(xrow + kk * 32);

#pragma unroll
  for (int c = 0; c < 8; c++) {
    f32x4 acc = {0.f, 0.f, 0.f, 0.f};
    const short* wrow = wb + (size_t)(16 * c + lr) * FDIM + lg * 8;
#pragma unroll
    for (int kk = 0; kk < 4; kk++) {
      bf16x8 B = *(const bf16x8*)(wrow + kk * 32);
      acc = __builtin_amdgcn_mfma_f32_16x16x32_bf16(A[kk], B, acc, 0, 0, 0);
    }
    int col = 16 * c + lr;
    float bc = bias[col];
#pragma unroll
    for (int j = 0; j < 4; j++) {
      int row = rb + lg * 4 + j;
      float z = acc[j] + bc + b2f(((const unsigned short*)mi)[(size_t)row * FDIM + col]);
      out[(size_t)row * FDIM + col] = gelu_exact(z);
    }
  }
}

extern "C" void kernel_launch(void* const* d_in, const int* in_sizes, int n_in,
                              void* d_out, int out_size, void* d_ws, size_t ws_size,
                              hipStream_t stream) {
  const float* x = (const float*)d_in[0];
  const float* action = (const float*)d_in[1];
  const float* wmsg = (const float*)d_in[2];
  const float* wupd = (const float*)d_in[3];
  const float* bupd = (const float*)d_in[4];
  const int* pn = (const int*)d_in[5];
  const int* pe = (const int*)d_in[6];
  float* out = (float*)d_out;

  char* p = (char*)d_ws;
  auto alloc = [&](size_t bytes) -> char* {
    char* r = p;
    p += (bytes + 255) & ~(size_t)255;
    return r;
  };
  short* xb = (short*)alloc((size_t)N_NODESC * FDIM * 2);
  short* mji = (short*)alloc((size_t)N_NODESC * FDIM * 2);
  short* mi = (short*)alloc((size_t)N_NODESC * FDIM * 2);
  short* efeat = (short*)alloc((size_t)N_EDGESC * FDIM * 2);
  int* sn = (int*)alloc((size_t)N_PAIRSC * 4);
  int* se = (int*)alloc((size_t)N_PAIRSC * 4);
  short* wmsgb = (short*)alloc(FDIM * FDIM * 2);
  short* wupdb = (short*)alloc(FDIM * FDIM * 2);
  float* send = (float*)alloc(N_NODESC * 4);
  float* recv = (float*)alloc(N_NODESC * 4);
  int* ecnt = (int*)alloc(N_EDGESC * 4);
  int* eoff = (int*)alloc(N_EDGESC * 4);
  int* ecur = (int*)alloc(N_EDGESC * 4);
  int* ncnt = (int*)alloc(N_NODESC * 4);
  int* noff = (int*)alloc(N_NODESC * 4);
  int* ncur = (int*)alloc(N_NODESC * 4);
  int* csum = (int*)alloc((NCH_E + NCH_N) * 4);

  k_zero<<<(N_NODESC + 255) / 256, 256, 0, stream>>>(ecnt, ncnt);
  k_prep<<<12500, 256, 0, stream>>>(x, action, wmsg, wupd, pn, pe, xb, wmsgb, wupdb, send, recv, ecnt, ncnt);
  k_chunksum<<<NCH_E + NCH_N, 256, 0, stream>>>(ecnt, ncnt, csum);
  k_scanchunks<<<1, 64, 0, stream>>>(csum);
  k_offsets<<<NCH_E + NCH_N, 256, 0, stream>>>(ecnt, ncnt, csum, eoff, ecur, noff, ncur);
  k_scatter<<<SC_NCHUNK * 8, 256, 0, stream>>>(pn, pe, ecur, ncur, sn, se);
  k_gemm_msg<<<1563, 256, 0, stream>>>(xb, wmsgb, send, mji);
  k_edge<<<2500, 256, 0, stream>>>(mji, sn, eoff, ecnt, efeat);
  k_node<<<25000, 256, 0, stream>>>(efeat, se, noff, ncnt, recv, mi);
  k_gemm_upd<<<1563, 256, 0, stream>>>(xb, wupdb, bupd, mi, out);
}

// Round 4
// 471.915 us; speedup vs baseline: 1.3323x; 1.1622x over previous
//
#include <hip/hip_runtime.h>

#define N_NODESC 100000
#define N_EDGESC 10000
#define N_PAIRSC 1600000
#define FDIM 128
#define NCH_E 40     // ceil(10000/256)
#define NCH_N 391    // ceil(100000/256)

#define SC_CHUNK 2048
#define SC_NCHUNK ((N_PAIRSC + SC_CHUNK - 1) / SC_CHUNK)  // 782

#define HC_CHUNK 25000
#define HC_NCHUNK 64   // 64 * 25000 = 1.6M

typedef short bf16x8 __attribute__((ext_vector_type(8)));
typedef float f32x4 __attribute__((ext_vector_type(4)));
typedef int i32x4 __attribute__((ext_vector_type(4)));

__device__ __forceinline__ unsigned short f2b(float f) {
  unsigned u = __float_as_uint(f);
  u += 0x7fffu + ((u >> 16) & 1u);
  return (unsigned short)(u >> 16);
}
__device__ __forceinline__ float b2f(unsigned short b) {
  return __uint_as_float(((unsigned)b) << 16);
}
__device__ __forceinline__ unsigned pack2(float a, float b) {
  return (unsigned)f2b(a) | ((unsigned)f2b(b) << 16);
}
__device__ __forceinline__ float gelu_exact(float z) {
  return 0.5f * z * (1.0f + erff(z * 0.70710678118f));
}

// ---------------- zero counters ----------------
__global__ __launch_bounds__(256) void k_zero(int* ecnt, int* ncnt) {
  int i = blockIdx.x * 256 + threadIdx.x;
  if (i < N_EDGESC) ecnt[i] = 0;
  if (i < N_NODESC) ncnt[i] = 0;
}

// ---------------- prep: pure streaming bf16 convert + send/recv ----------------
__global__ __launch_bounds__(256) void k_prep(const float* __restrict__ x, const float* __restrict__ action,
                                              const float* __restrict__ wmsg, const float* __restrict__ wupd,
                                              short* __restrict__ xb, short* __restrict__ wmsgb,
                                              short* __restrict__ wupdb, float* __restrict__ send,
                                              float* __restrict__ recv) {
  int i = blockIdx.x * 256 + threadIdx.x;
  if (i < (N_NODESC * FDIM) / 4) {
    const float4 v = ((const float4*)x)[i];
    uint2 o;
    o.x = pack2(v.x, v.y);
    o.y = pack2(v.z, v.w);
    ((uint2*)xb)[i] = o;
  }
  if (i < FDIM * FDIM) {
    wmsgb[i] = (short)f2b(wmsg[i]);
    wupdb[i] = (short)f2b(wupd[i]);
  }
  if (i < N_NODESC) {
    float a0 = action[i * 3 + 0], a1 = action[i * 3 + 1], a2 = action[i * 3 + 2];
    send[i] = a0 + a2;
    recv[i] = a0 + a1;
  }
}

// ---------------- histogram, XCD-range partitioned ----------------
// blockIdx%8 = range group r: edge bins [r*1250,(r+1)*1250) in a private LDS
// histogram (one contiguous XCD-local flush), node bins [r*12500,(r+1)*12500)
// via direct atomics whose lines stay resident in ONE XCD's L2 (no cross-XCD
// ownership ping-pong, which was k_prep's 165us pathology).
__global__ __launch_bounds__(256) void k_hist(const int* __restrict__ pn, const int* __restrict__ pe,
                                              int* __restrict__ ecnt, int* __restrict__ ncnt) {
  __shared__ int lh[N_EDGESC / 8];
  int r = blockIdx.x & 7;
  int c = blockIdx.x >> 3;
  for (int b = threadIdx.x; b < N_EDGESC / 8; b += 256) lh[b] = 0;
  __syncthreads();
  int elo = r * (N_EDGESC / 8), ehi = elo + (N_EDGESC / 8);
  int nlo = r * (N_NODESC / 8), nhi = nlo + (N_NODESC / 8);
  int base = c * HC_CHUNK;
  for (int q = threadIdx.x; q < HC_CHUNK / 4; q += 256) {
    int idx = base + q * 4;
    i32x4 e4 = __builtin_nontemporal_load((const i32x4*)(pe + idx));
    i32x4 v4 = __builtin_nontemporal_load((const i32x4*)(pn + idx));
#pragma unroll
    for (int j = 0; j < 4; j++) {
      int ee = e4[j], vv = v4[j];
      if (ee >= elo && ee < ehi) atomicAdd(&lh[ee - elo], 1);
      if (vv >= nlo && vv < nhi) atomicAdd(&ncnt[vv], 1);
    }
  }
  __syncthreads();
  for (int b = threadIdx.x; b < N_EDGESC / 8; b += 256) {
    int v = lh[b];
    if (v) atomicAdd(&ecnt[elo + b], v);
  }
}

// ---------------- scan helpers ----------------
__device__ __forceinline__ int wave_incl_scan(int v, int lane) {
#pragma unroll
  for (int d = 1; d < 64; d <<= 1) {
    int n = __shfl_up(v, d, 64);
    if (lane >= d) v += n;
  }
  return v;
}

// P1: per-256-chunk sums. blocks [0,NCH_E) -> edge, [NCH_E, NCH_E+NCH_N) -> node
__global__ __launch_bounds__(256) void k_chunksum(const int* __restrict__ ecnt, const int* __restrict__ ncnt,
                                                  int* __restrict__ csum) {
  int b = blockIdx.x, t = threadIdx.x, lane = t & 63, w = t >> 6;
  int v;
  if (b < NCH_E) {
    int i = b * 256 + t;
    v = (i < N_EDGESC) ? ecnt[i] : 0;
  } else {
    int i = (b - NCH_E) * 256 + t;
    v = (i < N_NODESC) ? ncnt[i] : 0;
  }
#pragma unroll
  for (int d = 32; d; d >>= 1) v += __shfl_down(v, d, 64);
  __shared__ int wsum[4];
  if (lane == 0) wsum[w] = v;
  __syncthreads();
  if (t == 0) csum[b] = wsum[0] + wsum[1] + wsum[2] + wsum[3];
}

// P2: exclusive-scan the chunk sums (two independent segments), single wave
__global__ void k_scanchunks(int* __restrict__ csum) {
  int lane = threadIdx.x;
  int carry = 0;
  for (int base = 0; base < NCH_E; base += 64) {
    int idx = base + lane;
    int v = (idx < NCH_E) ? csum[idx] : 0;
    int inc = wave_incl_scan(v, lane);
    if (idx < NCH_E) csum[idx] = carry + inc - v;
    carry += __shfl(inc, 63, 64);
  }
  carry = 0;
  for (int base = 0; base < NCH_N; base += 64) {
    int idx = base + lane;
    int v = (idx < NCH_N) ? csum[NCH_E + idx] : 0;
    int inc = wave_incl_scan(v, lane);
    if (idx < NCH_N) csum[NCH_E + idx] = carry + inc - v;
    carry += __shfl(inc, 63, 64);
  }
}

// P3: block-local exclusive scan + chunk base -> offsets & cursors
__global__ __launch_bounds__(256) void k_offsets(const int* __restrict__ ecnt, const int* __restrict__ ncnt,
                                                 const int* __restrict__ csum, int* __restrict__ eoff,
                                                 int* __restrict__ ecur, int* __restrict__ noff,
                                                 int* __restrict__ ncur) {
  int b = blockIdx.x, t = threadIdx.x, lane = t & 63, w = t >> 6;
  const int* cnt;
  int* off;
  int* cur;
  int i, n;
  if (b < NCH_E) {
    i = b * 256 + t; n = N_EDGESC; cnt = ecnt; off = eoff; cur = ecur;
  } else {
    i = (b - NCH_E) * 256 + t; n = N_NODESC; cnt = ncnt; off = noff; cur = ncur;
  }
  int base = csum[b];
  int v = (i < n) ? cnt[i] : 0;
  int inc = wave_incl_scan(v, lane);
  __shared__ int wsum[4], woff[4];
  if (lane == 63) wsum[w] = inc;
  __syncthreads();
  if (t == 0) {
    int s = 0;
#pragma unroll
    for (int k = 0; k < 4; k++) { woff[k] = s; s += wsum[k]; }
  }
  __syncthreads();
  int excl = base + woff[w] + inc - v;
  if (i < n) { off[i] = excl; cur[i] = excl; }
}

// ---------------- scatter into sorted order, XCD-range partitioned ----------------
__global__ __launch_bounds__(256) void k_scatter(const int* __restrict__ pn, const int* __restrict__ pe,
                                                 int* __restrict__ ecur, int* __restrict__ ncur,
                                                 int* __restrict__ sn, int* __restrict__ se) {
  int r = blockIdx.x & 7;
  int c = blockIdx.x >> 3;
  int base = c * SC_CHUNK;
  int elo = r * (N_EDGESC / 8), ehi = elo + (N_EDGESC / 8);
  int nlo = r * (N_NODESC / 8), nhi = nlo + (N_NODESC / 8);
#pragma unroll
  for (int k = 0; k < 2; k++) {
    int idx = base + k * 1024 + threadIdx.x * 4;
    if (idx >= N_PAIRSC) continue;
    i32x4 v4 = __builtin_nontemporal_load((const i32x4*)(pn + idx));
    i32x4 e4 = __builtin_nontemporal_load((const i32x4*)(pe + idx));
#pragma unroll
    for (int j = 0; j < 4; j++) {
      int vv = v4[j], ee = e4[j];
      if (ee >= elo && ee < ehi) {
        int pos = atomicAdd(&ecur[ee], 1);
        sn[pos] = vv;
      }
      if (vv >= nlo && vv < nhi) {
        int pos2 = atomicAdd(&ncur[vv], 1);
        se[pos2] = ee;
      }
    }
  }
}

// ---------------- GEMM 1: m_ji = gelu(x @ Wmsg^T) * send  -> bf16 ----------------
__global__ __launch_bounds__(256) void k_gemm_msg(const short* __restrict__ xb, const short* __restrict__ wb,
                                                  const float* __restrict__ send, short* __restrict__ mji) {
  int gw = (blockIdx.x * 256 + threadIdx.x) >> 6;
  int lane = threadIdx.x & 63;
  int rb = gw * 16;
  if (rb >= N_NODESC) return;
  int lr = lane & 15, lg = lane >> 4;

  bf16x8 A[4];
  const short* xrow = xb + (size_t)(rb + lr) * FDIM + lg * 8;
#pragma unroll
  for (int kk = 0; kk < 4; kk++) A[kk] = *(const bf16x8*)(xrow + kk * 32);

  float sv[4];
#pragma unroll
  for (int j = 0; j < 4; j++) sv[j] = send[rb + lg * 4 + j];

#pragma unroll
  for (int c = 0; c < 8; c++) {
    f32x4 acc = {0.f, 0.f, 0.f, 0.f};
    const short* wrow = wb + (size_t)(16 * c + lr) * FDIM + lg * 8;
#pragma unroll
    for (int kk = 0; kk < 4; kk++) {
      bf16x8 B = *(const bf16x8*)(wrow + kk * 32);
      acc = __builtin_amdgcn_mfma_f32_16x16x32_bf16(A[kk], B, acc, 0, 0, 0);
    }
#pragma unroll
    for (int j = 0; j < 4; j++) {
      float z = acc[j];
      float m = gelu_exact(z) * sv[j];
      int row = rb + lg * 4 + j, col = 16 * c + lr;
      mji[(size_t)row * FDIM + col] = (short)f2b(m);
    }
  }
}

// ---------------- edge reduce: e_feat = mean over pairs of m_ji[node] ----------------
__global__ __launch_bounds__(256) void k_edge(const short* __restrict__ mji, const int* __restrict__ sn,
                                              const int* __restrict__ eoff, const int* __restrict__ ecnt,
                                              short* __restrict__ efeat) {
  int wv = blockIdx.x * 4 + (threadIdx.x >> 6);
  int lane = threadIdx.x & 63;
  if (wv >= N_EDGESC) return;
  int beg = eoff[wv], cnt = ecnt[wv];
  float a0 = 0.f, a1 = 0.f;
#pragma unroll 4
  for (int p = 0; p < cnt; p++) {
    int node = sn[beg + p];
    unsigned u = *(const unsigned*)(mji + (size_t)node * FDIM + lane * 2);
    a0 += __uint_as_float(u << 16);
    a1 += __uint_as_float(u & 0xffff0000u);
  }
  float inv = 1.0f / fmaxf((float)cnt, 1.0f);
  ((unsigned*)(efeat + (size_t)wv * FDIM))[lane] = pack2(a0 * inv, a1 * inv);
}

// ---------------- node reduce: m_i = recv/deg * sum over pairs of e_feat[edge] ----------------
__global__ __launch_bounds__(256) void k_node(const short* __restrict__ efeat, const int* __restrict__ se,
                                              const int* __restrict__ noff, const int* __restrict__ ncnt,
                                              const float* __restrict__ recv, short* __restrict__ mi) {
  int wv = blockIdx.x * 4 + (threadIdx.x >> 6);
  int lane = threadIdx.x & 63;
  if (wv >= N_NODESC) return;
  int beg = noff[wv], cnt = ncnt[wv];
  float a0 = 0.f, a1 = 0.f;
#pragma unroll 4
  for (int p = 0; p < cnt; p++) {
    int e = se[beg + p];
    unsigned u = *(const unsigned*)(efeat + (size_t)e * FDIM + lane * 2);
    a0 += __uint_as_float(u << 16);
    a1 += __uint_as_float(u & 0xffff0000u);
  }
  float s = recv[wv] / fmaxf((float)cnt, 1.0f);
  ((unsigned*)(mi + (size_t)wv * FDIM))[lane] = pack2(a0 * s, a1 * s);
}

// ---------------- GEMM 2: out = gelu(x @ Wupd^T + b + m_i)  -> f32 ----------------
__global__ __launch_bounds__(256) void k_gemm_upd(const short* __restrict__ xb, const short* __restrict__ wb,
                                                  const float* __restrict__ bias, const short* __restrict__ mi,
                                                  float* __restrict__ out) {
  int gw = (blockIdx.x * 256 + threadIdx.x) >> 6;
  int lane = threadIdx.x & 63;
  int rb = gw * 16;
  if (rb >= N_NODESC) return;
  int lr = lane & 15, lg = lane >> 4;

  bf16x8 A[4];
  const short* xrow = xb + (size_t)(rb + lr) * FDIM + lg * 8;
#pragma unroll
  for (int kk = 0; kk < 4; kk++) A[kk] = *(const bf16x8*)(xrow + kk * 32);

#pragma unroll
  for (int c = 0; c < 8; c++) {
    f32x4 acc = {0.f, 0.f, 0.f, 0.f};
    const short* wrow = wb + (size_t)(16 * c + lr) * FDIM + lg * 8;
#pragma unroll
    for (int kk = 0; kk < 4; kk++) {
      bf16x8 B = *(const bf16x8*)(wrow + kk * 32);
      acc = __builtin_amdgcn_mfma_f32_16x16x32_bf16(A[kk], B, acc, 0, 0, 0);
    }
    int col = 16 * c + lr;
    float bc = bias[col];
#pragma unroll
    for (int j = 0; j < 4; j++) {
      int row = rb + lg * 4 + j;
      float z = acc[j] + bc + b2f(((const unsigned short*)mi)[(size_t)row * FDIM + col]);
      out[(size_t)row * FDIM + col] = gelu_exact(z);
    }
  }
}

extern "C" void kernel_launch(void* const* d_in, const int* in_sizes, int n_in,
                              void* d_out, int out_size, void* d_ws, size_t ws_size,
                              hipStream_t stream) {
  const float* x = (const float*)d_in[0];
  const float* action = (const float*)d_in[1];
  const float* wmsg = (const float*)d_in[2];
  const float* wupd = (const float*)d_in[3];
  const float* bupd = (const float*)d_in[4];
  const int* pn = (const int*)d_in[5];
  const int* pe = (const int*)d_in[6];
  float* out = (float*)d_out;

  char* p = (char*)d_ws;
  auto alloc = [&](size_t bytes) -> char* {
    char* r = p;
    p += (bytes + 255) & ~(size_t)255;
    return r;
  };
  short* xb = (short*)alloc((size_t)N_NODESC * FDIM * 2);
  short* mji = (short*)alloc((size_t)N_NODESC * FDIM * 2);
  short* mi = (short*)alloc((size_t)N_NODESC * FDIM * 2);
  short* efeat = (short*)alloc((size_t)N_EDGESC * FDIM * 2);
  int* sn = (int*)alloc((size_t)N_PAIRSC * 4);
  int* se = (int*)alloc((size_t)N_PAIRSC * 4);
  short* wmsgb = (short*)alloc(FDIM * FDIM * 2);
  short* wupdb = (short*)alloc(FDIM * FDIM * 2);
  float* send = (float*)alloc(N_NODESC * 4);
  float* recv = (float*)alloc(N_NODESC * 4);
  int* ecnt = (int*)alloc(N_EDGESC * 4);
  int* eoff = (int*)alloc(N_EDGESC * 4);
  int* ecur = (int*)alloc(N_EDGESC * 4);
  int* ncnt = (int*)alloc(N_NODESC * 4);
  int* noff = (int*)alloc(N_NODESC * 4);
  int* ncur = (int*)alloc(N_NODESC * 4);
  int* csum = (int*)alloc((NCH_E + NCH_N) * 4);

  k_zero<<<(N_NODESC + 255) / 256, 256, 0, stream>>>(ecnt, ncnt);
  k_prep<<<12500, 256, 0, stream>>>(x, action, wmsg, wupd, xb, wmsgb, wupdb, send, recv);
  k_hist<<<HC_NCHUNK * 8, 256, 0, stream>>>(pn, pe, ecnt, ncnt);
  k_chunksum<<<NCH_E + NCH_N, 256, 0, stream>>>(ecnt, ncnt, csum);
  k_scanchunks<<<1, 64, 0, stream>>>(csum);
  k_offsets<<<NCH_E + NCH_N, 256, 0, stream>>>(ecnt, ncnt, csum, eoff, ecur, noff, ncur);
  k_scatter<<<SC_NCHUNK * 8, 256, 0, stream>>>(pn, pe, ecur, ncur, sn, se);
  k_gemm_msg<<<1563, 256, 0, stream>>>(xb, wmsgb, send, mji);
  k_edge<<<2500, 256, 0, stream>>>(mji, sn, eoff, ecnt, efeat);
  k_node<<<25000, 256, 0, stream>>>(efeat, se, noff, ncnt, recv, mi);
  k_gemm_upd<<<1563, 256, 0, stream>>>(xb, wupdb, bupd, mi, out);
}

// Round 5
// 359.765 us; speedup vs baseline: 1.7476x; 1.3117x over previous
//
#include <hip/hip_runtime.h>

#define N_NODESC 100000
#define N_EDGESC 10000
#define N_PAIRSC 1600000
#define FDIM 128
#define NCH_E 40     // ceil(10000/256)
#define NCH_N 391    // ceil(100000/256)

#define HC_CHUNK 25000
#define HC_NCHUNK 64   // 64 * 25000 = 1.6M

#define NB 200       // buckets per path
#define EPB 50       // edges per bucket  (200*50 = 10000)
#define NPB 500      // nodes per bucket  (200*500 = 100000)
#define PA_CHUNK 8192
#define PA_NCH ((N_PAIRSC + PA_CHUNK - 1) / PA_CHUNK)  // 196

typedef short bf16x8 __attribute__((ext_vector_type(8)));
typedef float f32x4 __attribute__((ext_vector_type(4)));
typedef int i32x4 __attribute__((ext_vector_type(4)));

__device__ __forceinline__ unsigned short f2b(float f) {
  unsigned u = __float_as_uint(f);
  u += 0x7fffu + ((u >> 16) & 1u);
  return (unsigned short)(u >> 16);
}
__device__ __forceinline__ float b2f(unsigned short b) {
  return __uint_as_float(((unsigned)b) << 16);
}
__device__ __forceinline__ unsigned pack2(float a, float b) {
  return (unsigned)f2b(a) | ((unsigned)f2b(b) << 16);
}
__device__ __forceinline__ float gelu_exact(float z) {
  return 0.5f * z * (1.0f + erff(z * 0.70710678118f));
}

// ---------------- zero counters + bucket cursors ----------------
__global__ __launch_bounds__(256) void k_zero(int* ecnt, int* ncnt) {
  int i = blockIdx.x * 256 + threadIdx.x;
  if (i < N_EDGESC) ecnt[i] = 0;
  if (i < N_NODESC) ncnt[i] = 0;
}

// ---------------- prep: pure streaming bf16 convert + send/recv ----------------
__global__ __launch_bounds__(256) void k_prep(const float* __restrict__ x, const float* __restrict__ action,
                                              const float* __restrict__ wmsg, const float* __restrict__ wupd,
                                              short* __restrict__ xb, short* __restrict__ wmsgb,
                                              short* __restrict__ wupdb, float* __restrict__ send,
                                              float* __restrict__ recv) {
  int i = blockIdx.x * 256 + threadIdx.x;
  if (i < (N_NODESC * FDIM) / 4) {
    const float4 v = ((const float4*)x)[i];
    uint2 o;
    o.x = pack2(v.x, v.y);
    o.y = pack2(v.z, v.w);
    ((uint2*)xb)[i] = o;
  }
  if (i < FDIM * FDIM) {
    wmsgb[i] = (short)f2b(wmsg[i]);
    wupdb[i] = (short)f2b(wupd[i]);
  }
  if (i < N_NODESC) {
    float a0 = action[i * 3 + 0], a1 = action[i * 3 + 1], a2 = action[i * 3 + 2];
    send[i] = a0 + a2;
    recv[i] = a0 + a1;
  }
}

// ---------------- histogram, XCD-range partitioned (degrees) ----------------
__global__ __launch_bounds__(256) void k_hist(const int* __restrict__ pn, const int* __restrict__ pe,
                                              int* __restrict__ ecnt, int* __restrict__ ncnt) {
  __shared__ int lh[N_EDGESC / 8];
  int r = blockIdx.x & 7;
  int c = blockIdx.x >> 3;
  for (int b = threadIdx.x; b < N_EDGESC / 8; b += 256) lh[b] = 0;
  __syncthreads();
  int elo = r * (N_EDGESC / 8), ehi = elo + (N_EDGESC / 8);
  int nlo = r * (N_NODESC / 8), nhi = nlo + (N_NODESC / 8);
  int base = c * HC_CHUNK;
  for (int q = threadIdx.x; q < HC_CHUNK / 4; q += 256) {
    int idx = base + q * 4;
    i32x4 e4 = __builtin_nontemporal_load((const i32x4*)(pe + idx));
    i32x4 v4 = __builtin_nontemporal_load((const i32x4*)(pn + idx));
#pragma unroll
    for (int j = 0; j < 4; j++) {
      int ee = e4[j], vv = v4[j];
      if (ee >= elo && ee < ehi) atomicAdd(&lh[ee - elo], 1);
      if (vv >= nlo && vv < nhi) atomicAdd(&ncnt[vv], 1);
    }
  }
  __syncthreads();
  for (int b = threadIdx.x; b < N_EDGESC / 8; b += 256) {
    int v = lh[b];
    if (v) atomicAdd(&ecnt[elo + b], v);
  }
}

// ---------------- scan helpers ----------------
__device__ __forceinline__ int wave_incl_scan(int v, int lane) {
#pragma unroll
  for (int d = 1; d < 64; d <<= 1) {
    int n = __shfl_up(v, d, 64);
    if (lane >= d) v += n;
  }
  return v;
}

__global__ __launch_bounds__(256) void k_chunksum(const int* __restrict__ ecnt, const int* __restrict__ ncnt,
                                                  int* __restrict__ csum) {
  int b = blockIdx.x, t = threadIdx.x, lane = t & 63, w = t >> 6;
  int v;
  if (b < NCH_E) {
    int i = b * 256 + t;
    v = (i < N_EDGESC) ? ecnt[i] : 0;
  } else {
    int i = (b - NCH_E) * 256 + t;
    v = (i < N_NODESC) ? ncnt[i] : 0;
  }
#pragma unroll
  for (int d = 32; d; d >>= 1) v += __shfl_down(v, d, 64);
  __shared__ int wsum[4];
  if (lane == 0) wsum[w] = v;
  __syncthreads();
  if (t == 0) csum[b] = wsum[0] + wsum[1] + wsum[2] + wsum[3];
}

__global__ void k_scanchunks(int* __restrict__ csum) {
  int lane = threadIdx.x;
  int carry = 0;
  for (int base = 0; base < NCH_E; base += 64) {
    int idx = base + lane;
    int v = (idx < NCH_E) ? csum[idx] : 0;
    int inc = wave_incl_scan(v, lane);
    if (idx < NCH_E) csum[idx] = carry + inc - v;
    carry += __shfl(inc, 63, 64);
  }
  carry = 0;
  for (int base = 0; base < NCH_N; base += 64) {
    int idx = base + lane;
    int v = (idx < NCH_N) ? csum[NCH_E + idx] : 0;
    int inc = wave_incl_scan(v, lane);
    if (idx < NCH_N) csum[NCH_E + idx] = carry + inc - v;
    carry += __shfl(inc, 63, 64);
  }
}

__global__ __launch_bounds__(256) void k_offsets(const int* __restrict__ ecnt, const int* __restrict__ ncnt,
                                                 const int* __restrict__ csum, int* __restrict__ eoff,
                                                 int* __restrict__ noff) {
  int b = blockIdx.x, t = threadIdx.x, lane = t & 63, w = t >> 6;
  const int* cnt;
  int* off;
  int i, n;
  if (b < NCH_E) {
    i = b * 256 + t; n = N_EDGESC; cnt = ecnt; off = eoff;
  } else {
    i = (b - NCH_E) * 256 + t; n = N_NODESC; cnt = ncnt; off = noff;
  }
  int base = csum[b];
  int v = (i < n) ? cnt[i] : 0;
  int inc = wave_incl_scan(v, lane);
  __shared__ int wsum[4], woff[4];
  if (lane == 63) wsum[w] = inc;
  __syncthreads();
  if (t == 0) {
    int s = 0;
#pragma unroll
    for (int k = 0; k < 4; k++) { woff[k] = s; s += wsum[k]; }
  }
  __syncthreads();
  int excl = base + woff[w] + inc - v;
  if (i < n) off[i] = excl;
}

// ---------------- init bucket cursors from segment offsets ----------------
__global__ __launch_bounds__(256) void k_initcur(const int* __restrict__ eoff, const int* __restrict__ noff,
                                                 int* __restrict__ gcure, int* __restrict__ gcurn) {
  int i = threadIdx.x;
  if (i < NB) {
    gcure[i] = eoff[i * EPB];
    gcurn[i] = noff[i * NPB];
  }
}

// ---------------- phase A: coarse bucket partition ----------------
// 196 blocks (<=1/CU). Per block: LDS count per bucket -> one global atomic
// reservation per bucket -> write (key,val) as 8B items in ~41-item runs
// (mostly full cache lines). Bucket arrays are laid out at the FINAL segment
// offsets, so bucket b's region is exactly [eoff[b*EPB], eoff[(b+1)*EPB]).
__global__ __launch_bounds__(256) void k_part(const int* __restrict__ pn, const int* __restrict__ pe,
                                              int* __restrict__ gcure, int* __restrict__ gcurn,
                                              unsigned long long* __restrict__ buckE,
                                              unsigned long long* __restrict__ buckN) {
  __shared__ int ce[NB], cn[NB];
  int t = threadIdx.x;
  for (int i = t; i < NB; i += 256) { ce[i] = 0; cn[i] = 0; }
  __syncthreads();
  long long base = (long long)blockIdx.x * PA_CHUNK;
  // pass 1: count per bucket
  for (int q = t; q < PA_CHUNK / 4; q += 256) {
    long long idx = base + (long long)q * 4;
    if (idx >= N_PAIRSC) break;
    i32x4 e4 = __builtin_nontemporal_load((const i32x4*)(pe + idx));
    i32x4 v4 = __builtin_nontemporal_load((const i32x4*)(pn + idx));
#pragma unroll
    for (int j = 0; j < 4; j++) {
      atomicAdd(&ce[e4[j] / EPB], 1);
      atomicAdd(&cn[v4[j] / NPB], 1);
    }
  }
  __syncthreads();
  // reserve global ranges; LDS counters become running cursors
  for (int i = t; i < NB; i += 256) {
    ce[i] = atomicAdd(&gcure[i], ce[i]);
    cn[i] = atomicAdd(&gcurn[i], cn[i]);
  }
  __syncthreads();
  // pass 2: place items
  for (int q = t; q < PA_CHUNK / 4; q += 256) {
    long long idx = base + (long long)q * 4;
    if (idx >= N_PAIRSC) break;
    i32x4 e4 = __builtin_nontemporal_load((const i32x4*)(pe + idx));
    i32x4 v4 = __builtin_nontemporal_load((const i32x4*)(pn + idx));
#pragma unroll
    for (int j = 0; j < 4; j++) {
      int ee = e4[j], vv = v4[j];
      int p1 = atomicAdd(&ce[ee / EPB], 1);
      buckE[p1] = (unsigned long long)(unsigned)ee | ((unsigned long long)(unsigned)vv << 32);
      int p2 = atomicAdd(&cn[vv / NPB], 1);
      buckN[p2] = (unsigned long long)(unsigned)vv | ((unsigned long long)(unsigned)ee << 32);
    }
  }
}

// ---------------- phase B: fine scatter within single-block-owned window ----------------
// One block per bucket; all stores land in the block's own ~32KB contiguous
// window, resident in its XCD L2 for the block's short lifetime -> full-line
// writebacks regardless of the block->XCD mapping.
__global__ __launch_bounds__(256) void k_fine(const unsigned long long* __restrict__ buckE,
                                              const unsigned long long* __restrict__ buckN,
                                              const int* __restrict__ eoff, const int* __restrict__ noff,
                                              int* __restrict__ sn, int* __restrict__ se) {
  __shared__ int cur[NPB];
  int b = blockIdx.x, t = threadIdx.x;
  if (b < NB) {
    int elo = b * EPB;
    for (int i = t; i < EPB; i += 256) cur[i] = eoff[elo + i];
    int beg = eoff[elo];
    int end = (b == NB - 1) ? N_PAIRSC : eoff[elo + EPB];
    __syncthreads();
    for (int i = beg + t; i < end; i += 256) {
      unsigned long long u = buckE[i];
      int key = (int)(unsigned)u, val = (int)(u >> 32);
      int pos = atomicAdd(&cur[key - elo], 1);
      sn[pos] = val;
    }
  } else {
    int bb = b - NB;
    int nlo = bb * NPB;
    for (int i = t; i < NPB; i += 256) cur[i] = noff[nlo + i];
    int beg = noff[nlo];
    int end = (bb == NB - 1) ? N_PAIRSC : noff[nlo + NPB];
    __syncthreads();
    for (int i = beg + t; i < end; i += 256) {
      unsigned long long u = buckN[i];
      int key = (int)(unsigned)u, val = (int)(u >> 32);
      int pos = atomicAdd(&cur[key - nlo], 1);
      se[pos] = val;
    }
  }
}

// ---------------- GEMM 1: m_ji = gelu(x @ Wmsg^T) * send  -> bf16 ----------------
__global__ __launch_bounds__(256) void k_gemm_msg(const short* __restrict__ xb, const short* __restrict__ wb,
                                                  const float* __restrict__ send, short* __restrict__ mji) {
  int gw = (blockIdx.x * 256 + threadIdx.x) >> 6;
  int lane = threadIdx.x & 63;
  int rb = gw * 16;
  if (rb >= N_NODESC) return;
  int lr = lane & 15, lg = lane >> 4;

  bf16x8 A[4];
  const short* xrow = xb + (size_t)(rb + lr) * FDIM + lg * 8;
#pragma unroll
  for (int kk = 0; kk < 4; kk++) A[kk] = *(const bf16x8*)(xrow + kk * 32);

  float sv[4];
#pragma unroll
  for (int j = 0; j < 4; j++) sv[j] = send[rb + lg * 4 + j];

#pragma unroll
  for (int c = 0; c < 8; c++) {
    f32x4 acc = {0.f, 0.f, 0.f, 0.f};
    const short* wrow = wb + (size_t)(16 * c + lr) * FDIM + lg * 8;
#pragma unroll
    for (int kk = 0; kk < 4; kk++) {
      bf16x8 B = *(const bf16x8*)(wrow + kk * 32);
      acc = __builtin_amdgcn_mfma_f32_16x16x32_bf16(A[kk], B, acc, 0, 0, 0);
    }
#pragma unroll
    for (int j = 0; j < 4; j++) {
      float z = acc[j];
      float m = gelu_exact(z) * sv[j];
      int row = rb + lg * 4 + j, col = 16 * c + lr;
      mji[(size_t)row * FDIM + col] = (short)f2b(m);
    }
  }
}

// ---------------- edge reduce: e_feat = mean over pairs of m_ji[node] ----------------
__global__ __launch_bounds__(256) void k_edge(const short* __restrict__ mji, const int* __restrict__ sn,
                                              const int* __restrict__ eoff, const int* __restrict__ ecnt,
                                              short* __restrict__ efeat) {
  int wv = blockIdx.x * 4 + (threadIdx.x >> 6);
  int lane = threadIdx.x & 63;
  if (wv >= N_EDGESC) return;
  int beg = eoff[wv], cnt = ecnt[wv];
  float a0 = 0.f, a1 = 0.f;
#pragma unroll 4
  for (int p = 0; p < cnt; p++) {
    int node = sn[beg + p];
    unsigned u = *(const unsigned*)(mji + (size_t)node * FDIM + lane * 2);
    a0 += __uint_as_float(u << 16);
    a1 += __uint_as_float(u & 0xffff0000u);
  }
  float inv = 1.0f / fmaxf((float)cnt, 1.0f);
  ((unsigned*)(efeat + (size_t)wv * FDIM))[lane] = pack2(a0 * inv, a1 * inv);
}

// ---------------- node reduce: m_i = recv/deg * sum over pairs of e_feat[edge] ----------------
__global__ __launch_bounds__(256) void k_node(const short* __restrict__ efeat, const int* __restrict__ se,
                                              const int* __restrict__ noff, const int* __restrict__ ncnt,
                                              const float* __restrict__ recv, short* __restrict__ mi) {
  int wv = blockIdx.x * 4 + (threadIdx.x >> 6);
  int lane = threadIdx.x & 63;
  if (wv >= N_NODESC) return;
  int beg = noff[wv], cnt = ncnt[wv];
  float a0 = 0.f, a1 = 0.f;
#pragma unroll 4
  for (int p = 0; p < cnt; p++) {
    int e = se[beg + p];
    unsigned u = *(const unsigned*)(efeat + (size_t)e * FDIM + lane * 2);
    a0 += __uint_as_float(u << 16);
    a1 += __uint_as_float(u & 0xffff0000u);
  }
  float s = recv[wv] / fmaxf((float)cnt, 1.0f);
  ((unsigned*)(mi + (size_t)wv * FDIM))[lane] = pack2(a0 * s, a1 * s);
}

// ---------------- GEMM 2: out = gelu(x @ Wupd^T + b + m_i)  -> f32 ----------------
__global__ __launch_bounds__(256) void k_gemm_upd(const short* __restrict__ xb, const short* __restrict__ wb,
                                                  const float* __restrict__ bias, const short* __restrict__ mi,
                                                  float* __restrict__ out) {
  int gw = (blockIdx.x * 256 + threadIdx.x) >> 6;
  int lane = threadIdx.x & 63;
  int rb = gw * 16;
  if (rb >= N_NODESC) return;
  int lr = lane & 15, lg = lane >> 4;

  bf16x8 A[4];
  const short* xrow = xb + (size_t)(rb + lr) * FDIM + lg * 8;
#pragma unroll
  for (int kk = 0; kk < 4; kk++) A[kk] = *(const bf16x8*)(xrow + kk * 32);

#pragma unroll
  for (int c = 0; c < 8; c++) {
    f32x4 acc = {0.f, 0.f, 0.f, 0.f};
    const short* wrow = wb + (size_t)(16 * c + lr) * FDIM + lg * 8;
#pragma unroll
    for (int kk = 0; kk < 4; kk++) {
      bf16x8 B = *(const bf16x8*)(wrow + kk * 32);
      acc = __builtin_amdgcn_mfma_f32_16x16x32_bf16(A[kk], B, acc, 0, 0, 0);
    }
    int col = 16 * c + lr;
    float bc = bias[col];
#pragma unroll
    for (int j = 0; j < 4; j++) {
      int row = rb + lg * 4 + j;
      float z = acc[j] + bc + b2f(((const unsigned short*)mi)[(size_t)row * FDIM + col]);
      out[(size_t)row * FDIM + col] = gelu_exact(z);
    }
  }
}

extern "C" void kernel_launch(void* const* d_in, const int* in_sizes, int n_in,
                              void* d_out, int out_size, void* d_ws, size_t ws_size,
                              hipStream_t stream) {
  const float* x = (const float*)d_in[0];
  const float* action = (const float*)d_in[1];
  const float* wmsg = (const float*)d_in[2];
  const float* wupd = (const float*)d_in[3];
  const float* bupd = (const float*)d_in[4];
  const int* pn = (const int*)d_in[5];
  const int* pe = (const int*)d_in[6];
  float* out = (float*)d_out;

  char* p = (char*)d_ws;
  auto alloc = [&](size_t bytes) -> char* {
    char* r = p;
    p += (bytes + 255) & ~(size_t)255;
    return r;
  };
  short* xb = (short*)alloc((size_t)N_NODESC * FDIM * 2);
  short* mji = (short*)alloc((size_t)N_NODESC * FDIM * 2);
  short* mi = (short*)alloc((size_t)N_NODESC * FDIM * 2);   // also hosts buckE+buckN (used before k_node writes mi)
  short* efeat = (short*)alloc((size_t)N_EDGESC * FDIM * 2);
  int* sn = (int*)alloc((size_t)N_PAIRSC * 4);
  int* se = (int*)alloc((size_t)N_PAIRSC * 4);
  short* wmsgb = (short*)alloc(FDIM * FDIM * 2);
  short* wupdb = (short*)alloc(FDIM * FDIM * 2);
  float* send = (float*)alloc(N_NODESC * 4);
  float* recv = (float*)alloc(N_NODESC * 4);
  int* ecnt = (int*)alloc(N_EDGESC * 4);
  int* eoff = (int*)alloc(N_EDGESC * 4);
  int* ncnt = (int*)alloc(N_NODESC * 4);
  int* noff = (int*)alloc(N_NODESC * 4);
  int* csum = (int*)alloc((NCH_E + NCH_N) * 4);
  int* gcure = (int*)alloc(NB * 4);
  int* gcurn = (int*)alloc(NB * 4);

  unsigned long long* buckE = (unsigned long long*)mi;             // 12.8 MB
  unsigned long long* buckN = buckE + (size_t)N_PAIRSC;            // 12.8 MB  (= 25.6 MB total, fits in mi's region)

  k_zero<<<(N_NODESC + 255) / 256, 256, 0, stream>>>(ecnt, ncnt);
  k_prep<<<12500, 256, 0, stream>>>(x, action, wmsg, wupd, xb, wmsgb, wupdb, send, recv);
  k_hist<<<HC_NCHUNK * 8, 256, 0, stream>>>(pn, pe, ecnt, ncnt);
  k_chunksum<<<NCH_E + NCH_N, 256, 0, stream>>>(ecnt, ncnt, csum);
  k_scanchunks<<<1, 64, 0, stream>>>(csum);
  k_offsets<<<NCH_E + NCH_N, 256, 0, stream>>>(ecnt, ncnt, csum, eoff, noff);
  k_initcur<<<1, 256, 0, stream>>>(eoff, noff, gcure, gcurn);
  k_part<<<PA_NCH, 256, 0, stream>>>(pn, pe, gcure, gcurn, buckE, buckN);
  k_fine<<<2 * NB, 256, 0, stream>>>(buckE, buckN, eoff, noff, sn, se);
  k_gemm_msg<<<1563, 256, 0, stream>>>(xb, wmsgb, send, mji);
  k_edge<<<2500, 256, 0, stream>>>(mji, sn, eoff, ecnt, efeat);
  k_node<<<25000, 256, 0, stream>>>(efeat, se, noff, ncnt, recv, mi);
  k_gemm_upd<<<1563, 256, 0, stream>>>(xb, wupdb, bupd, mi, out);
}

// Round 6
// 290.163 us; speedup vs baseline: 2.1668x; 1.2399x over previous
//
#include <hip/hip_runtime.h>

#define N_NODESC 100000
#define N_EDGESC 10000
#define N_PAIRSC 1600000
#define FDIM 128

#define NB 200       // buckets per path
#define EPB 50       // edges per bucket  (200*50 = 10000)
#define NPB 500      // nodes per bucket  (200*500 = 100000)
#define PA_CHUNK 8192
#define PA_NCH ((N_PAIRSC + PA_CHUNK - 1) / PA_CHUNK)  // 196

#define BH_BLOCKS 250
#define BH_CHUNK 6400   // 250 * 6400 = 1.6M exactly

typedef short bf16x8 __attribute__((ext_vector_type(8)));
typedef float f32x4 __attribute__((ext_vector_type(4)));
typedef int i32x4 __attribute__((ext_vector_type(4)));

__device__ __forceinline__ unsigned short f2b(float f) {
  unsigned u = __float_as_uint(f);
  u += 0x7fffu + ((u >> 16) & 1u);
  return (unsigned short)(u >> 16);
}
__device__ __forceinline__ float b2f(unsigned short b) {
  return __uint_as_float(((unsigned)b) << 16);
}
__device__ __forceinline__ unsigned pack2(float a, float b) {
  return (unsigned)f2b(a) | ((unsigned)f2b(b) << 16);
}
__device__ __forceinline__ float gelu_exact(float z) {
  return 0.5f * z * (1.0f + erff(z * 0.70710678118f));
}
__device__ __forceinline__ float blo(unsigned u) { return __uint_as_float(u << 16); }
__device__ __forceinline__ float bhi(unsigned u) { return __uint_as_float(u & 0xffff0000u); }

// ---------------- prep: pure streaming bf16 convert + send/recv ----------------
__global__ __launch_bounds__(256) void k_prep(const float* __restrict__ x, const float* __restrict__ action,
                                              const float* __restrict__ wmsg, const float* __restrict__ wupd,
                                              short* __restrict__ xb, short* __restrict__ wmsgb,
                                              short* __restrict__ wupdb, float* __restrict__ send,
                                              float* __restrict__ recv) {
  int i = blockIdx.x * 256 + threadIdx.x;
  if (i < (N_NODESC * FDIM) / 4) {
    const float4 v = ((const float4*)x)[i];
    uint2 o;
    o.x = pack2(v.x, v.y);
    o.y = pack2(v.z, v.w);
    ((uint2*)xb)[i] = o;
  }
  if (i < FDIM * FDIM) {
    wmsgb[i] = (short)f2b(wmsg[i]);
    wupdb[i] = (short)f2b(wupd[i]);
  }
  if (i < N_NODESC) {
    float a0 = action[i * 3 + 0], a1 = action[i * 3 + 1], a2 = action[i * 3 + 2];
    send[i] = a0 + a2;
    recv[i] = a0 + a1;
  }
}

// ---------------- bucket histogram: per-block LDS 400 bins -> coalesced partials ----------------
__global__ __launch_bounds__(256) void k_bhist(const int* __restrict__ pn, const int* __restrict__ pe,
                                               int* __restrict__ part) {
  __shared__ int h[2 * NB];
  int t = threadIdx.x;
  for (int i = t; i < 2 * NB; i += 256) h[i] = 0;
  __syncthreads();
  int base = blockIdx.x * BH_CHUNK;
  for (int q = t; q < BH_CHUNK / 4; q += 256) {
    int idx = base + q * 4;
    i32x4 e4 = __builtin_nontemporal_load((const i32x4*)(pe + idx));
    i32x4 v4 = __builtin_nontemporal_load((const i32x4*)(pn + idx));
#pragma unroll
    for (int j = 0; j < 4; j++) {
      atomicAdd(&h[e4[j] / EPB], 1);
      atomicAdd(&h[NB + v4[j] / NPB], 1);
    }
  }
  __syncthreads();
  for (int i = t; i < 2 * NB; i += 256) part[blockIdx.x * 2 * NB + i] = h[i];
}

// ---------------- scan helper ----------------
__device__ __forceinline__ int wave_incl_scan(int v, int lane) {
#pragma unroll
  for (int d = 1; d < 64; d <<= 1) {
    int n = __shfl_up(v, d, 64);
    if (lane >= d) v += n;
  }
  return v;
}

// ---------------- reduce partials + scan bucket bases + init cursors ----------------
__global__ __launch_bounds__(256) void k_bscan(const int* __restrict__ part, int* __restrict__ ebase,
                                               int* __restrict__ nbase, int* __restrict__ gcure,
                                               int* __restrict__ gcurn) {
  __shared__ int tot[2 * NB];
  int t = threadIdx.x;
  for (int i = t; i < 2 * NB; i += 256) {
    int s = 0;
    for (int b = 0; b < BH_BLOCKS; b++) s += part[b * 2 * NB + i];
    tot[i] = s;
  }
  __syncthreads();
  if (t < 64) {
    int carry = 0;
    for (int base = 0; base < NB; base += 64) {
      int idx = base + t;
      int v = (idx < NB) ? tot[idx] : 0;
      int inc = wave_incl_scan(v, t);
      if (idx < NB) { ebase[idx] = carry + inc - v; gcure[idx] = carry + inc - v; }
      carry += __shfl(inc, 63, 64);
    }
    if (t == 0) ebase[NB] = N_PAIRSC;
  } else if (t < 128) {
    int lane = t - 64;
    int carry = 0;
    for (int base = 0; base < NB; base += 64) {
      int idx = base + lane;
      int v = (idx < NB) ? tot[NB + idx] : 0;
      int inc = wave_incl_scan(v, lane);
      if (idx < NB) { nbase[idx] = carry + inc - v; gcurn[idx] = carry + inc - v; }
      carry += __shfl(inc, 63, 64);
    }
    if (lane == 0) nbase[NB] = N_PAIRSC;
  }
}

// ---------------- phase A: coarse bucket partition ----------------
__global__ __launch_bounds__(256) void k_part(const int* __restrict__ pn, const int* __restrict__ pe,
                                              int* __restrict__ gcure, int* __restrict__ gcurn,
                                              unsigned long long* __restrict__ buckE,
                                              unsigned long long* __restrict__ buckN) {
  __shared__ int ce[NB], cn[NB];
  int t = threadIdx.x;
  for (int i = t; i < NB; i += 256) { ce[i] = 0; cn[i] = 0; }
  __syncthreads();
  long long base = (long long)blockIdx.x * PA_CHUNK;
  for (int q = t; q < PA_CHUNK / 4; q += 256) {
    long long idx = base + (long long)q * 4;
    if (idx >= N_PAIRSC) break;
    i32x4 e4 = __builtin_nontemporal_load((const i32x4*)(pe + idx));
    i32x4 v4 = __builtin_nontemporal_load((const i32x4*)(pn + idx));
#pragma unroll
    for (int j = 0; j < 4; j++) {
      atomicAdd(&ce[e4[j] / EPB], 1);
      atomicAdd(&cn[v4[j] / NPB], 1);
    }
  }
  __syncthreads();
  for (int i = t; i < NB; i += 256) {
    ce[i] = atomicAdd(&gcure[i], ce[i]);
    cn[i] = atomicAdd(&gcurn[i], cn[i]);
  }
  __syncthreads();
  for (int q = t; q < PA_CHUNK / 4; q += 256) {
    long long idx = base + (long long)q * 4;
    if (idx >= N_PAIRSC) break;
    i32x4 e4 = __builtin_nontemporal_load((const i32x4*)(pe + idx));
    i32x4 v4 = __builtin_nontemporal_load((const i32x4*)(pn + idx));
#pragma unroll
    for (int j = 0; j < 4; j++) {
      int ee = e4[j], vv = v4[j];
      int p1 = atomicAdd(&ce[ee / EPB], 1);
      buckE[p1] = (unsigned long long)(unsigned)ee | ((unsigned long long)(unsigned)vv << 32);
      int p2 = atomicAdd(&cn[vv / NPB], 1);
      buckN[p2] = (unsigned long long)(unsigned)vv | ((unsigned long long)(unsigned)ee << 32);
    }
  }
}

// ---------------- phase B: fine scatter + per-key counts/offsets from bucket ----------------
// One block per bucket. The bucket holds ALL pairs for its key range, so the
// per-key histogram + scan here produces the exact global ecnt/eoff (ncnt/noff)
// and the sorted lists, in one short-lived single-block-owned output window.
__global__ __launch_bounds__(256) void k_fine(const unsigned long long* __restrict__ buckE,
                                              const unsigned long long* __restrict__ buckN,
                                              const int* __restrict__ ebase, const int* __restrict__ nbase,
                                              int* __restrict__ ecnt, int* __restrict__ eoff,
                                              int* __restrict__ ncnt, int* __restrict__ noff,
                                              int* __restrict__ sn, int* __restrict__ se) {
  __shared__ int cnt_s[NPB], cur_s[NPB];
  int b = blockIdx.x, t = threadIdx.x;
  const unsigned long long* buck;
  int *kcnt, *koff, *out;
  int keys, lo, beg, end;
  if (b < NB) {
    buck = buckE; kcnt = ecnt; koff = eoff; out = sn;
    keys = EPB; lo = b * EPB; beg = ebase[b]; end = ebase[b + 1];
  } else {
    int bb = b - NB;
    buck = buckN; kcnt = ncnt; koff = noff; out = se;
    keys = NPB; lo = bb * NPB; beg = nbase[bb]; end = nbase[bb + 1];
  }
  for (int i = t; i < keys; i += 256) cnt_s[i] = 0;
  __syncthreads();
  for (int i = beg + t; i < end; i += 256) {
    int key = (int)(unsigned)buck[i] - lo;
    atomicAdd(&cnt_s[key], 1);
  }
  __syncthreads();
  if (t < 64) {
    int carry = beg;
    for (int base = 0; base < keys; base += 64) {
      int idx = base + t;
      int v = (idx < keys) ? cnt_s[idx] : 0;
      int inc = wave_incl_scan(v, t);
      if (idx < keys) cur_s[idx] = carry + inc - v;
      carry += __shfl(inc, 63, 64);
    }
  }
  __syncthreads();
  for (int i = t; i < keys; i += 256) {
    kcnt[lo + i] = cnt_s[i];
    koff[lo + i] = cur_s[i];
  }
  __syncthreads();
  for (int i = beg + t; i < end; i += 256) {
    unsigned long long u = buck[i];
    int key = (int)(unsigned)u - lo;
    int val = (int)(u >> 32);
    int pos = atomicAdd(&cur_s[key], 1);
    out[pos] = val;
  }
}

// ---------------- GEMM 1: m_ji = gelu(x @ Wmsg^T) * send  -> bf16 ----------------
__global__ __launch_bounds__(256) void k_gemm_msg(const short* __restrict__ xb, const short* __restrict__ wb,
                                                  const float* __restrict__ send, short* __restrict__ mji) {
  int gw = (blockIdx.x * 256 + threadIdx.x) >> 6;
  int lane = threadIdx.x & 63;
  int rb = gw * 16;
  if (rb >= N_NODESC) return;
  int lr = lane & 15, lg = lane >> 4;

  bf16x8 A[4];
  const short* xrow = xb + (size_t)(rb + lr) * FDIM + lg * 8;
#pragma unroll
  for (int kk = 0; kk < 4; kk++) A[kk] = *(const bf16x8*)(xrow + kk * 32);

  float sv[4];
#pragma unroll
  for (int j = 0; j < 4; j++) sv[j] = send[rb + lg * 4 + j];

#pragma unroll
  for (int c = 0; c < 8; c++) {
    f32x4 acc = {0.f, 0.f, 0.f, 0.f};
    const short* wrow = wb + (size_t)(16 * c + lr) * FDIM + lg * 8;
#pragma unroll
    for (int kk = 0; kk < 4; kk++) {
      bf16x8 B = *(const bf16x8*)(wrow + kk * 32);
      acc = __builtin_amdgcn_mfma_f32_16x16x32_bf16(A[kk], B, acc, 0, 0, 0);
    }
#pragma unroll
    for (int j = 0; j < 4; j++) {
      float z = acc[j];
      float m = gelu_exact(z) * sv[j];
      int row = rb + lg * 4 + j, col = 16 * c + lr;
      mji[(size_t)row * FDIM + col] = (short)f2b(m);
    }
  }
}

// ---------------- edge reduce: 2 pairs/wave, 32 lanes x 8B per row ----------------
__global__ __launch_bounds__(256) void k_edge(const short* __restrict__ mji, const int* __restrict__ sn,
                                              const int* __restrict__ eoff, const int* __restrict__ ecnt,
                                              short* __restrict__ efeat) {
  int wv = blockIdx.x * 4 + (threadIdx.x >> 6);
  int lane = threadIdx.x & 63;
  if (wv >= N_EDGESC) return;
  int beg = eoff[wv], cnt = ecnt[wv];
  int half = lane >> 5, c2 = lane & 31;
  float a0 = 0.f, a1 = 0.f, a2 = 0.f, a3 = 0.f;
#pragma unroll 4
  for (int p = half; p < cnt; p += 2) {
    int node = sn[beg + p];
    uint2 u = *(const uint2*)(mji + (size_t)node * FDIM + c2 * 4);
    a0 += blo(u.x); a1 += bhi(u.x);
    a2 += blo(u.y); a3 += bhi(u.y);
  }
  a0 += __shfl_xor(a0, 32, 64);
  a1 += __shfl_xor(a1, 32, 64);
  a2 += __shfl_xor(a2, 32, 64);
  a3 += __shfl_xor(a3, 32, 64);
  if (half == 0) {
    float inv = 1.0f / fmaxf((float)cnt, 1.0f);
    uint2 o;
    o.x = pack2(a0 * inv, a1 * inv);
    o.y = pack2(a2 * inv, a3 * inv);
    ((uint2*)(efeat + (size_t)wv * FDIM))[c2] = o;
  }
}

// ---------------- node reduce: 2 pairs/wave, 32 lanes x 8B per row ----------------
__global__ __launch_bounds__(256) void k_node(const short* __restrict__ efeat, const int* __restrict__ se,
                                              const int* __restrict__ noff, const int* __restrict__ ncnt,
                                              const float* __restrict__ recv, short* __restrict__ mi) {
  int wv = blockIdx.x * 4 + (threadIdx.x >> 6);
  int lane = threadIdx.x & 63;
  if (wv >= N_NODESC) return;
  int beg = noff[wv], cnt = ncnt[wv];
  int half = lane >> 5, c2 = lane & 31;
  float a0 = 0.f, a1 = 0.f, a2 = 0.f, a3 = 0.f;
#pragma unroll 4
  for (int p = half; p < cnt; p += 2) {
    int e = se[beg + p];
    uint2 u = *(const uint2*)(efeat + (size_t)e * FDIM + c2 * 4);
    a0 += blo(u.x); a1 += bhi(u.x);
    a2 += blo(u.y); a3 += bhi(u.y);
  }
  a0 += __shfl_xor(a0, 32, 64);
  a1 += __shfl_xor(a1, 32, 64);
  a2 += __shfl_xor(a2, 32, 64);
  a3 += __shfl_xor(a3, 32, 64);
  if (half == 0) {
    float s = recv[wv] / fmaxf((float)cnt, 1.0f);
    uint2 o;
    o.x = pack2(a0 * s, a1 * s);
    o.y = pack2(a2 * s, a3 * s);
    ((uint2*)(mi + (size_t)wv * FDIM))[c2] = o;
  }
}

// ---------------- GEMM 2: out = gelu(x @ Wupd^T + b + m_i)  -> f32 ----------------
__global__ __launch_bounds__(256) void k_gemm_upd(const short* __restrict__ xb, const short* __restrict__ wb,
                                                  const float* __restrict__ bias, const short* __restrict__ mi,
                                                  float* __restrict__ out) {
  int gw = (blockIdx.x * 256 + threadIdx.x) >> 6;
  int lane = threadIdx.x & 63;
  int rb = gw * 16;
  if (rb >= N_NODESC) return;
  int lr = lane & 15, lg = lane >> 4;

  bf16x8 A[4];
  const short* xrow = xb + (size_t)(rb + lr) * FDIM + lg * 8;
#pragma unroll
  for (int kk = 0; kk < 4; kk++) A[kk] = *(const bf16x8*)(xrow + kk * 32);

#pragma unroll
  for (int c = 0; c < 8; c++) {
    f32x4 acc = {0.f, 0.f, 0.f, 0.f};
    const short* wrow = wb + (size_t)(16 * c + lr) * FDIM + lg * 8;
#pragma unroll
    for (int kk = 0; kk < 4; kk++) {
      bf16x8 B = *(const bf16x8*)(wrow + kk * 32);
      acc = __builtin_amdgcn_mfma_f32_16x16x32_bf16(A[kk], B, acc, 0, 0, 0);
    }
    int col = 16 * c + lr;
    float bc = bias[col];
#pragma unroll
    for (int j = 0; j < 4; j++) {
      int row = rb + lg * 4 + j;
      float z = acc[j] + bc + b2f(((const unsigned short*)mi)[(size_t)row * FDIM + col]);
      out[(size_t)row * FDIM + col] = gelu_exact(z);
    }
  }
}

extern "C" void kernel_launch(void* const* d_in, const int* in_sizes, int n_in,
                              void* d_out, int out_size, void* d_ws, size_t ws_size,
                              hipStream_t stream) {
  const float* x = (const float*)d_in[0];
  const float* action = (const float*)d_in[1];
  const float* wmsg = (const float*)d_in[2];
  const float* wupd = (const float*)d_in[3];
  const float* bupd = (const float*)d_in[4];
  const int* pn = (const int*)d_in[5];
  const int* pe = (const int*)d_in[6];
  float* out = (float*)d_out;

  char* p = (char*)d_ws;
  auto alloc = [&](size_t bytes) -> char* {
    char* r = p;
    p += (bytes + 255) & ~(size_t)255;
    return r;
  };
  short* xb = (short*)alloc((size_t)N_NODESC * FDIM * 2);
  short* mji = (short*)alloc((size_t)N_NODESC * FDIM * 2);
  short* mi = (short*)alloc((size_t)N_NODESC * FDIM * 2);   // also hosts buckE+buckN (consumed before k_node writes mi)
  short* efeat = (short*)alloc((size_t)N_EDGESC * FDIM * 2);
  int* sn = (int*)alloc((size_t)N_PAIRSC * 4);
  int* se = (int*)alloc((size_t)N_PAIRSC * 4);
  short* wmsgb = (short*)alloc(FDIM * FDIM * 2);
  short* wupdb = (short*)alloc(FDIM * FDIM * 2);
  float* send = (float*)alloc(N_NODESC * 4);
  float* recv = (float*)alloc(N_NODESC * 4);
  int* ecnt = (int*)alloc(N_EDGESC * 4);
  int* eoff = (int*)alloc(N_EDGESC * 4);
  int* ncnt = (int*)alloc(N_NODESC * 4);
  int* noff = (int*)alloc(N_NODESC * 4);
  int* part = (int*)alloc((size_t)BH_BLOCKS * 2 * NB * 4);
  int* ebase = (int*)alloc((NB + 1) * 4);
  int* nbase = (int*)alloc((NB + 1) * 4);
  int* gcure = (int*)alloc(NB * 4);
  int* gcurn = (int*)alloc(NB * 4);

  unsigned long long* buckE = (unsigned long long*)mi;             // 12.8 MB
  unsigned long long* buckN = buckE + (size_t)N_PAIRSC;            // 12.8 MB (fits mi's 25.6 MB region)

  k_prep<<<12500, 256, 0, stream>>>(x, action, wmsg, wupd, xb, wmsgb, wupdb, send, recv);
  k_bhist<<<BH_BLOCKS, 256, 0, stream>>>(pn, pe, part);
  k_bscan<<<1, 256, 0, stream>>>(part, ebase, nbase, gcure, gcurn);
  k_part<<<PA_NCH, 256, 0, stream>>>(pn, pe, gcure, gcurn, buckE, buckN);
  k_fine<<<2 * NB, 256, 0, stream>>>(buckE, buckN, ebase, nbase, ecnt, eoff, ncnt, noff, sn, se);
  k_gemm_msg<<<1563, 256, 0, stream>>>(xb, wmsgb, send, mji);
  k_edge<<<2500, 256, 0, stream>>>(mji, sn, eoff, ecnt, efeat);
  k_node<<<25000, 256, 0, stream>>>(efeat, se, noff, ncnt, recv, mi);
  k_gemm_upd<<<1563, 256, 0, stream>>>(xb, wupdb, bupd, mi, out);
}

// Round 7
// 279.754 us; speedup vs baseline: 2.2474x; 1.0372x over previous
//
#include <hip/hip_runtime.h>

#define N_NODESC 100000
#define N_EDGESC 10000
#define N_PAIRSC 1600000
#define FDIM 128

#define NB 200       // buckets per path
#define EPB 50       // edges per bucket  (200*50 = 10000)
#define NPB 500      // nodes per bucket  (200*500 = 100000)
#define PA_CHUNK 8192
#define PA_NCH ((N_PAIRSC + PA_CHUNK - 1) / PA_CHUNK)  // 196

#define BH_BLOCKS 250
#define BH_CHUNK 6400   // 250 * 6400 = 1.6M exactly

typedef short bf16x8 __attribute__((ext_vector_type(8)));
typedef float f32x4 __attribute__((ext_vector_type(4)));
typedef int i32x4 __attribute__((ext_vector_type(4)));
typedef unsigned u32x4 __attribute__((ext_vector_type(4)));

__device__ __forceinline__ unsigned short f2b(float f) {
  unsigned u = __float_as_uint(f);
  u += 0x7fffu + ((u >> 16) & 1u);
  return (unsigned short)(u >> 16);
}
__device__ __forceinline__ float b2f(unsigned short b) {
  return __uint_as_float(((unsigned)b) << 16);
}
__device__ __forceinline__ unsigned pack2(float a, float b) {
  return (unsigned)f2b(a) | ((unsigned)f2b(b) << 16);
}
__device__ __forceinline__ float gelu_exact(float z) {
  return 0.5f * z * (1.0f + erff(z * 0.70710678118f));
}
__device__ __forceinline__ float blo(unsigned u) { return __uint_as_float(u << 16); }
__device__ __forceinline__ float bhi(unsigned u) { return __uint_as_float(u & 0xffff0000u); }

// ---------------- prep: pure streaming bf16 convert + send/recv ----------------
__global__ __launch_bounds__(256) void k_prep(const float* __restrict__ x, const float* __restrict__ action,
                                              const float* __restrict__ wmsg, const float* __restrict__ wupd,
                                              short* __restrict__ xb, short* __restrict__ wmsgb,
                                              short* __restrict__ wupdb, float* __restrict__ send,
                                              float* __restrict__ recv) {
  int i = blockIdx.x * 256 + threadIdx.x;
  if (i < (N_NODESC * FDIM) / 4) {
    const float4 v = ((const float4*)x)[i];
    uint2 o;
    o.x = pack2(v.x, v.y);
    o.y = pack2(v.z, v.w);
    ((uint2*)xb)[i] = o;
  }
  if (i < FDIM * FDIM) {
    wmsgb[i] = (short)f2b(wmsg[i]);
    wupdb[i] = (short)f2b(wupd[i]);
  }
  if (i < N_NODESC) {
    float a0 = action[i * 3 + 0], a1 = action[i * 3 + 1], a2 = action[i * 3 + 2];
    send[i] = a0 + a2;
    recv[i] = a0 + a1;
  }
}

// ---------------- bucket histogram: per-block LDS 400 bins -> coalesced partials ----------------
__global__ __launch_bounds__(256) void k_bhist(const int* __restrict__ pn, const int* __restrict__ pe,
                                               int* __restrict__ part) {
  __shared__ int h[2 * NB];
  int t = threadIdx.x;
  for (int i = t; i < 2 * NB; i += 256) h[i] = 0;
  __syncthreads();
  int base = blockIdx.x * BH_CHUNK;
  for (int q = t; q < BH_CHUNK / 4; q += 256) {
    int idx = base + q * 4;
    i32x4 e4 = __builtin_nontemporal_load((const i32x4*)(pe + idx));
    i32x4 v4 = __builtin_nontemporal_load((const i32x4*)(pn + idx));
#pragma unroll
    for (int j = 0; j < 4; j++) {
      atomicAdd(&h[e4[j] / EPB], 1);
      atomicAdd(&h[NB + v4[j] / NPB], 1);
    }
  }
  __syncthreads();
  for (int i = t; i < 2 * NB; i += 256) part[blockIdx.x * 2 * NB + i] = h[i];
}

// ---------------- scan helper ----------------
__device__ __forceinline__ int wave_incl_scan(int v, int lane) {
#pragma unroll
  for (int d = 1; d < 64; d <<= 1) {
    int n = __shfl_up(v, d, 64);
    if (lane >= d) v += n;
  }
  return v;
}

// ---------------- reduce partials + scan bucket bases + init cursors ----------------
__global__ __launch_bounds__(256) void k_bscan(const int* __restrict__ part, int* __restrict__ ebase,
                                               int* __restrict__ nbase, int* __restrict__ gcure,
                                               int* __restrict__ gcurn) {
  __shared__ int tot[2 * NB];
  int t = threadIdx.x;
  for (int i = t; i < 2 * NB; i += 256) {
    int s = 0;
    for (int b = 0; b < BH_BLOCKS; b++) s += part[b * 2 * NB + i];
    tot[i] = s;
  }
  __syncthreads();
  if (t < 64) {
    int carry = 0;
    for (int base = 0; base < NB; base += 64) {
      int idx = base + t;
      int v = (idx < NB) ? tot[idx] : 0;
      int inc = wave_incl_scan(v, t);
      if (idx < NB) { ebase[idx] = carry + inc - v; gcure[idx] = carry + inc - v; }
      carry += __shfl(inc, 63, 64);
    }
    if (t == 0) ebase[NB] = N_PAIRSC;
  } else if (t < 128) {
    int lane = t - 64;
    int carry = 0;
    for (int base = 0; base < NB; base += 64) {
      int idx = base + lane;
      int v = (idx < NB) ? tot[NB + idx] : 0;
      int inc = wave_incl_scan(v, lane);
      if (idx < NB) { nbase[idx] = carry + inc - v; gcurn[idx] = carry + inc - v; }
      carry += __shfl(inc, 63, 64);
    }
    if (lane == 0) nbase[NB] = N_PAIRSC;
  }
}

// ---------------- phase A: coarse bucket partition ----------------
__global__ __launch_bounds__(256) void k_part(const int* __restrict__ pn, const int* __restrict__ pe,
                                              int* __restrict__ gcure, int* __restrict__ gcurn,
                                              unsigned long long* __restrict__ buckE,
                                              unsigned long long* __restrict__ buckN) {
  __shared__ int ce[NB], cn[NB];
  int t = threadIdx.x;
  for (int i = t; i < NB; i += 256) { ce[i] = 0; cn[i] = 0; }
  __syncthreads();
  long long base = (long long)blockIdx.x * PA_CHUNK;
  for (int q = t; q < PA_CHUNK / 4; q += 256) {
    long long idx = base + (long long)q * 4;
    if (idx >= N_PAIRSC) break;
    i32x4 e4 = __builtin_nontemporal_load((const i32x4*)(pe + idx));
    i32x4 v4 = __builtin_nontemporal_load((const i32x4*)(pn + idx));
#pragma unroll
    for (int j = 0; j < 4; j++) {
      atomicAdd(&ce[e4[j] / EPB], 1);
      atomicAdd(&cn[v4[j] / NPB], 1);
    }
  }
  __syncthreads();
  for (int i = t; i < NB; i += 256) {
    ce[i] = atomicAdd(&gcure[i], ce[i]);
    cn[i] = atomicAdd(&gcurn[i], cn[i]);
  }
  __syncthreads();
  for (int q = t; q < PA_CHUNK / 4; q += 256) {
    long long idx = base + (long long)q * 4;
    if (idx >= N_PAIRSC) break;
    i32x4 e4 = __builtin_nontemporal_load((const i32x4*)(pe + idx));
    i32x4 v4 = __builtin_nontemporal_load((const i32x4*)(pn + idx));
#pragma unroll
    for (int j = 0; j < 4; j++) {
      int ee = e4[j], vv = v4[j];
      int p1 = atomicAdd(&ce[ee / EPB], 1);
      buckE[p1] = (unsigned long long)(unsigned)ee | ((unsigned long long)(unsigned)vv << 32);
      int p2 = atomicAdd(&cn[vv / NPB], 1);
      buckN[p2] = (unsigned long long)(unsigned)vv | ((unsigned long long)(unsigned)ee << 32);
    }
  }
}

// ---------------- phase B: fine scatter + per-key counts/offsets from bucket ----------------
__global__ __launch_bounds__(256) void k_fine(const unsigned long long* __restrict__ buckE,
                                              const unsigned long long* __restrict__ buckN,
                                              const int* __restrict__ ebase, const int* __restrict__ nbase,
                                              int* __restrict__ ecnt, int* __restrict__ eoff,
                                              int* __restrict__ ncnt, int* __restrict__ noff,
                                              int* __restrict__ sn, int* __restrict__ se) {
  __shared__ int cnt_s[NPB], cur_s[NPB];
  int b = blockIdx.x, t = threadIdx.x;
  const unsigned long long* buck;
  int *kcnt, *koff, *out;
  int keys, lo, beg, end;
  if (b < NB) {
    buck = buckE; kcnt = ecnt; koff = eoff; out = sn;
    keys = EPB; lo = b * EPB; beg = ebase[b]; end = ebase[b + 1];
  } else {
    int bb = b - NB;
    buck = buckN; kcnt = ncnt; koff = noff; out = se;
    keys = NPB; lo = bb * NPB; beg = nbase[bb]; end = nbase[bb + 1];
  }
  for (int i = t; i < keys; i += 256) cnt_s[i] = 0;
  __syncthreads();
  for (int i = beg + t; i < end; i += 256) {
    int key = (int)(unsigned)buck[i] - lo;
    atomicAdd(&cnt_s[key], 1);
  }
  __syncthreads();
  if (t < 64) {
    int carry = beg;
    for (int base = 0; base < keys; base += 64) {
      int idx = base + t;
      int v = (idx < keys) ? cnt_s[idx] : 0;
      int inc = wave_incl_scan(v, t);
      if (idx < keys) cur_s[idx] = carry + inc - v;
      carry += __shfl(inc, 63, 64);
    }
  }
  __syncthreads();
  for (int i = t; i < keys; i += 256) {
    kcnt[lo + i] = cnt_s[i];
    koff[lo + i] = cur_s[i];
  }
  __syncthreads();
  for (int i = beg + t; i < end; i += 256) {
    unsigned long long u = buck[i];
    int key = (int)(unsigned)u - lo;
    int val = (int)(u >> 32);
    int pos = atomicAdd(&cur_s[key], 1);
    out[pos] = val;
  }
}

// ---------------- GEMM 1: m_ji = gelu(x @ Wmsg^T) * send  -> bf16 ----------------
__global__ __launch_bounds__(256) void k_gemm_msg(const short* __restrict__ xb, const short* __restrict__ wb,
                                                  const float* __restrict__ send, short* __restrict__ mji) {
  int gw = (blockIdx.x * 256 + threadIdx.x) >> 6;
  int lane = threadIdx.x & 63;
  int rb = gw * 16;
  if (rb >= N_NODESC) return;
  int lr = lane & 15, lg = lane >> 4;

  bf16x8 A[4];
  const short* xrow = xb + (size_t)(rb + lr) * FDIM + lg * 8;
#pragma unroll
  for (int kk = 0; kk < 4; kk++) A[kk] = *(const bf16x8*)(xrow + kk * 32);

  float sv[4];
#pragma unroll
  for (int j = 0; j < 4; j++) sv[j] = send[rb + lg * 4 + j];

#pragma unroll
  for (int c = 0; c < 8; c++) {
    f32x4 acc = {0.f, 0.f, 0.f, 0.f};
    const short* wrow = wb + (size_t)(16 * c + lr) * FDIM + lg * 8;
#pragma unroll
    for (int kk = 0; kk < 4; kk++) {
      bf16x8 B = *(const bf16x8*)(wrow + kk * 32);
      acc = __builtin_amdgcn_mfma_f32_16x16x32_bf16(A[kk], B, acc, 0, 0, 0);
    }
#pragma unroll
    for (int j = 0; j < 4; j++) {
      float z = acc[j];
      float m = gelu_exact(z) * sv[j];
      int row = rb + lg * 4 + j, col = 16 * c + lr;
      mji[(size_t)row * FDIM + col] = (short)f2b(m);
    }
  }
}

// ---------------- edge reduce: 4 pairs/wave, 16 lanes x 16B per row ----------------
__global__ __launch_bounds__(256) void k_edge(const short* __restrict__ mji, const int* __restrict__ sn,
                                              const int* __restrict__ eoff, const int* __restrict__ ecnt,
                                              short* __restrict__ efeat) {
  int wv = blockIdx.x * 4 + (threadIdx.x >> 6);
  int lane = threadIdx.x & 63;
  if (wv >= N_EDGESC) return;
  int beg = eoff[wv], cnt = ecnt[wv];
  int sub = lane >> 4, c4 = lane & 15;
  float a0 = 0.f, a1 = 0.f, a2 = 0.f, a3 = 0.f;
  float a4 = 0.f, a5 = 0.f, a6 = 0.f, a7 = 0.f;
#pragma unroll 4
  for (int p = sub; p < cnt; p += 4) {
    int node = sn[beg + p];
    u32x4 u = *(const u32x4*)(mji + (size_t)node * FDIM + c4 * 8);
    a0 += blo(u[0]); a1 += bhi(u[0]);
    a2 += blo(u[1]); a3 += bhi(u[1]);
    a4 += blo(u[2]); a5 += bhi(u[2]);
    a6 += blo(u[3]); a7 += bhi(u[3]);
  }
#pragma unroll
  for (int d = 16; d <= 32; d <<= 1) {
    a0 += __shfl_xor(a0, d, 64); a1 += __shfl_xor(a1, d, 64);
    a2 += __shfl_xor(a2, d, 64); a3 += __shfl_xor(a3, d, 64);
    a4 += __shfl_xor(a4, d, 64); a5 += __shfl_xor(a5, d, 64);
    a6 += __shfl_xor(a6, d, 64); a7 += __shfl_xor(a7, d, 64);
  }
  if (sub == 0) {
    float inv = 1.0f / fmaxf((float)cnt, 1.0f);
    u32x4 o;
    o[0] = pack2(a0 * inv, a1 * inv);
    o[1] = pack2(a2 * inv, a3 * inv);
    o[2] = pack2(a4 * inv, a5 * inv);
    o[3] = pack2(a6 * inv, a7 * inv);
    ((u32x4*)(efeat + (size_t)wv * FDIM))[c4] = o;
  }
}

// ---------------- node reduce: 4 pairs/wave, 16 lanes x 16B per row ----------------
__global__ __launch_bounds__(256) void k_node(const short* __restrict__ efeat, const int* __restrict__ se,
                                              const int* __restrict__ noff, const int* __restrict__ ncnt,
                                              const float* __restrict__ recv, short* __restrict__ mi) {
  int wv = blockIdx.x * 4 + (threadIdx.x >> 6);
  int lane = threadIdx.x & 63;
  if (wv >= N_NODESC) return;
  int beg = noff[wv], cnt = ncnt[wv];
  int sub = lane >> 4, c4 = lane & 15;
  float a0 = 0.f, a1 = 0.f, a2 = 0.f, a3 = 0.f;
  float a4 = 0.f, a5 = 0.f, a6 = 0.f, a7 = 0.f;
#pragma unroll 4
  for (int p = sub; p < cnt; p += 4) {
    int e = se[beg + p];
    u32x4 u = *(const u32x4*)(efeat + (size_t)e * FDIM + c4 * 8);
    a0 += blo(u[0]); a1 += bhi(u[0]);
    a2 += blo(u[1]); a3 += bhi(u[1]);
    a4 += blo(u[2]); a5 += bhi(u[2]);
    a6 += blo(u[3]); a7 += bhi(u[3]);
  }
#pragma unroll
  for (int d = 16; d <= 32; d <<= 1) {
    a0 += __shfl_xor(a0, d, 64); a1 += __shfl_xor(a1, d, 64);
    a2 += __shfl_xor(a2, d, 64); a3 += __shfl_xor(a3, d, 64);
    a4 += __shfl_xor(a4, d, 64); a5 += __shfl_xor(a5, d, 64);
    a6 += __shfl_xor(a6, d, 64); a7 += __shfl_xor(a7, d, 64);
  }
  if (sub == 0) {
    float s = recv[wv] / fmaxf((float)cnt, 1.0f);
    u32x4 o;
    o[0] = pack2(a0 * s, a1 * s);
    o[1] = pack2(a2 * s, a3 * s);
    o[2] = pack2(a4 * s, a5 * s);
    o[3] = pack2(a6 * s, a7 * s);
    ((u32x4*)(mi + (size_t)wv * FDIM))[c4] = o;
  }
}

// ---------------- GEMM 2: out = gelu(x @ Wupd^T + b + m_i)  -> f32 ----------------
__global__ __launch_bounds__(256) void k_gemm_upd(const short* __restrict__ xb, const short* __restrict__ wb,
                                                  const float* __restrict__ bias, const short* __restrict__ mi,
                                                  float* __restrict__ out) {
  int gw = (blockIdx.x * 256 + threadIdx.x) >> 6;
  int lane = threadIdx.x & 63;
  int rb = gw * 16;
  if (rb >= N_NODESC) return;
  int lr = lane & 15, lg = lane >> 4;

  bf16x8 A[4];
  const short* xrow = xb + (size_t)(rb + lr) * FDIM + lg * 8;
#pragma unroll
  for (int kk = 0; kk < 4; kk++) A[kk] = *(const bf16x8*)(xrow + kk * 32);

#pragma unroll
  for (int c = 0; c < 8; c++) {
    f32x4 acc = {0.f, 0.f, 0.f, 0.f};
    const short* wrow = wb + (size_t)(16 * c + lr) * FDIM + lg * 8;
#pragma unroll
    for (int kk = 0; kk < 4; kk++) {
      bf16x8 B = *(const bf16x8*)(wrow + kk * 32);
      acc = __builtin_amdgcn_mfma_f32_16x16x32_bf16(A[kk], B, acc, 0, 0, 0);
    }
    int col = 16 * c + lr;
    float bc = bias[col];
#pragma unroll
    for (int j = 0; j < 4; j++) {
      int row = rb + lg * 4 + j;
      float z = acc[j] + bc + b2f(((const unsigned short*)mi)[(size_t)row * FDIM + col]);
      out[(size_t)row * FDIM + col] = gelu_exact(z);
    }
  }
}

extern "C" void kernel_launch(void* const* d_in, const int* in_sizes, int n_in,
                              void* d_out, int out_size, void* d_ws, size_t ws_size,
                              hipStream_t stream) {
  const float* x = (const float*)d_in[0];
  const float* action = (const float*)d_in[1];
  const float* wmsg = (const float*)d_in[2];
  const float* wupd = (const float*)d_in[3];
  const float* bupd = (const float*)d_in[4];
  const int* pn = (const int*)d_in[5];
  const int* pe = (const int*)d_in[6];
  float* out = (float*)d_out;

  char* p = (char*)d_ws;
  auto alloc = [&](size_t bytes) -> char* {
    char* r = p;
    p += (bytes + 255) & ~(size_t)255;
    return r;
  };
  short* xb = (short*)alloc((size_t)N_NODESC * FDIM * 2);
  short* mji = (short*)alloc((size_t)N_NODESC * FDIM * 2);
  short* mi = (short*)alloc((size_t)N_NODESC * FDIM * 2);   // also hosts buckE+buckN (consumed before k_node writes mi)
  short* efeat = (short*)alloc((size_t)N_EDGESC * FDIM * 2);
  int* sn = (int*)alloc((size_t)N_PAIRSC * 4);
  int* se = (int*)alloc((size_t)N_PAIRSC * 4);
  short* wmsgb = (short*)alloc(FDIM * FDIM * 2);
  short* wupdb = (short*)alloc(FDIM * FDIM * 2);
  float* send = (float*)alloc(N_NODESC * 4);
  float* recv = (float*)alloc(N_NODESC * 4);
  int* ecnt = (int*)alloc(N_EDGESC * 4);
  int* eoff = (int*)alloc(N_EDGESC * 4);
  int* ncnt = (int*)alloc(N_NODESC * 4);
  int* noff = (int*)alloc(N_NODESC * 4);
  int* part = (int*)alloc((size_t)BH_BLOCKS * 2 * NB * 4);
  int* ebase = (int*)alloc((NB + 1) * 4);
  int* nbase = (int*)alloc((NB + 1) * 4);
  int* gcure = (int*)alloc(NB * 4);
  int* gcurn = (int*)alloc(NB * 4);

  unsigned long long* buckE = (unsigned long long*)mi;             // 12.8 MB
  unsigned long long* buckN = buckE + (size_t)N_PAIRSC;            // 12.8 MB (fits mi's 25.6 MB region)

  k_prep<<<12500, 256, 0, stream>>>(x, action, wmsg, wupd, xb, wmsgb, wupdb, send, recv);
  k_bhist<<<BH_BLOCKS, 256, 0, stream>>>(pn, pe, part);
  k_bscan<<<1, 256, 0, stream>>>(part, ebase, nbase, gcure, gcurn);
  k_part<<<PA_NCH, 256, 0, stream>>>(pn, pe, gcure, gcurn, buckE, buckN);
  k_fine<<<2 * NB, 256, 0, stream>>>(buckE, buckN, ebase, nbase, ecnt, eoff, ncnt, noff, sn, se);
  k_gemm_msg<<<1563, 256, 0, stream>>>(xb, wmsgb, send, mji);
  k_edge<<<2500, 256, 0, stream>>>(mji, sn, eoff, ecnt, efeat);
  k_node<<<25000, 256, 0, stream>>>(efeat, se, noff, ncnt, recv, mi);
  k_gemm_upd<<<1563, 256, 0, stream>>>(xb, wupdb, bupd, mi, out);
}

// Round 8
// 251.390 us; speedup vs baseline: 2.5010x; 1.1128x over previous
//
#include <hip/hip_runtime.h>

#define N_NODESC 100000
#define N_EDGESC 10000
#define N_PAIRSC 1600000
#define FDIM 128

#define NB 200       // buckets per path
#define EPB 50       // edges per bucket  (200*50 = 10000)
#define NPB 500      // nodes per bucket  (200*500 = 100000)
#define PA_CHUNK 8192
#define PA_NCH ((N_PAIRSC + PA_CHUNK - 1) / PA_CHUNK)  // 196

#define BH_BLOCKS 250
#define BH_CHUNK 6400   // 250 * 6400 = 1.6M exactly

typedef short bf16x8 __attribute__((ext_vector_type(8)));
typedef float f32x4 __attribute__((ext_vector_type(4)));
typedef float f32x2 __attribute__((ext_vector_type(2)));
typedef int i32x4 __attribute__((ext_vector_type(4)));
typedef unsigned u32x4 __attribute__((ext_vector_type(4)));

__device__ __forceinline__ unsigned short f2b(float f) {
  unsigned u = __float_as_uint(f);
  u += 0x7fffu + ((u >> 16) & 1u);
  return (unsigned short)(u >> 16);
}
__device__ __forceinline__ float b2f(unsigned short b) {
  return __uint_as_float(((unsigned)b) << 16);
}
__device__ __forceinline__ unsigned pack2(float a, float b) {
  return (unsigned)f2b(a) | ((unsigned)f2b(b) << 16);
}
__device__ __forceinline__ float gelu_exact(float z) {
  return 0.5f * z * (1.0f + erff(z * 0.70710678118f));
}

// ---------------- prep: pure streaming bf16 convert + send/recv ----------------
__global__ __launch_bounds__(256) void k_prep(const float* __restrict__ x, const float* __restrict__ action,
                                              const float* __restrict__ wmsg, const float* __restrict__ wupd,
                                              short* __restrict__ xb, short* __restrict__ wmsgb,
                                              short* __restrict__ wupdb, float* __restrict__ send,
                                              float* __restrict__ recv) {
  int i = blockIdx.x * 256 + threadIdx.x;
  if (i < (N_NODESC * FDIM) / 4) {
    const float4 v = ((const float4*)x)[i];
    uint2 o;
    o.x = pack2(v.x, v.y);
    o.y = pack2(v.z, v.w);
    ((uint2*)xb)[i] = o;
  }
  if (i < FDIM * FDIM) {
    wmsgb[i] = (short)f2b(wmsg[i]);
    wupdb[i] = (short)f2b(wupd[i]);
  }
  if (i < N_NODESC) {
    float a0 = action[i * 3 + 0], a1 = action[i * 3 + 1], a2 = action[i * 3 + 2];
    send[i] = a0 + a2;
    recv[i] = a0 + a1;
  }
}

// ---------------- bucket histogram: per-block LDS 400 bins -> coalesced partials ----------------
__global__ __launch_bounds__(256) void k_bhist(const int* __restrict__ pn, const int* __restrict__ pe,
                                               int* __restrict__ part) {
  __shared__ int h[2 * NB];
  int t = threadIdx.x;
  for (int i = t; i < 2 * NB; i += 256) h[i] = 0;
  __syncthreads();
  int base = blockIdx.x * BH_CHUNK;
  for (int q = t; q < BH_CHUNK / 4; q += 256) {
    int idx = base + q * 4;
    i32x4 e4 = __builtin_nontemporal_load((const i32x4*)(pe + idx));
    i32x4 v4 = __builtin_nontemporal_load((const i32x4*)(pn + idx));
#pragma unroll
    for (int j = 0; j < 4; j++) {
      atomicAdd(&h[e4[j] / EPB], 1);
      atomicAdd(&h[NB + v4[j] / NPB], 1);
    }
  }
  __syncthreads();
  for (int i = t; i < 2 * NB; i += 256) part[blockIdx.x * 2 * NB + i] = h[i];
}

// ---------------- scan helper ----------------
__device__ __forceinline__ int wave_incl_scan(int v, int lane) {
#pragma unroll
  for (int d = 1; d < 64; d <<= 1) {
    int n = __shfl_up(v, d, 64);
    if (lane >= d) v += n;
  }
  return v;
}

// ---------------- reduce partials + scan bucket bases + init cursors ----------------
__global__ __launch_bounds__(256) void k_bscan(const int* __restrict__ part, int* __restrict__ ebase,
                                               int* __restrict__ nbase, int* __restrict__ gcure,
                                               int* __restrict__ gcurn) {
  __shared__ int tot[2 * NB];
  int t = threadIdx.x;
  for (int i = t; i < 2 * NB; i += 256) {
    int s = 0;
    for (int b = 0; b < BH_BLOCKS; b++) s += part[b * 2 * NB + i];
    tot[i] = s;
  }
  __syncthreads();
  if (t < 64) {
    int carry = 0;
    for (int base = 0; base < NB; base += 64) {
      int idx = base + t;
      int v = (idx < NB) ? tot[idx] : 0;
      int inc = wave_incl_scan(v, t);
      if (idx < NB) { ebase[idx] = carry + inc - v; gcure[idx] = carry + inc - v; }
      carry += __shfl(inc, 63, 64);
    }
    if (t == 0) ebase[NB] = N_PAIRSC;
  } else if (t < 128) {
    int lane = t - 64;
    int carry = 0;
    for (int base = 0; base < NB; base += 64) {
      int idx = base + lane;
      int v = (idx < NB) ? tot[NB + idx] : 0;
      int inc = wave_incl_scan(v, lane);
      if (idx < NB) { nbase[idx] = carry + inc - v; gcurn[idx] = carry + inc - v; }
      carry += __shfl(inc, 63, 64);
    }
    if (lane == 0) nbase[NB] = N_PAIRSC;
  }
}

// ---------------- phase A: coarse bucket partition (31-bit packed items) ----------------
__global__ __launch_bounds__(256) void k_part(const int* __restrict__ pn, const int* __restrict__ pe,
                                              int* __restrict__ gcure, int* __restrict__ gcurn,
                                              unsigned* __restrict__ buckE,
                                              unsigned* __restrict__ buckN) {
  __shared__ int ce[NB], cn[NB];
  int t = threadIdx.x;
  for (int i = t; i < NB; i += 256) { ce[i] = 0; cn[i] = 0; }
  __syncthreads();
  long long base = (long long)blockIdx.x * PA_CHUNK;
  for (int q = t; q < PA_CHUNK / 4; q += 256) {
    long long idx = base + (long long)q * 4;
    if (idx >= N_PAIRSC) break;
    i32x4 e4 = __builtin_nontemporal_load((const i32x4*)(pe + idx));
    i32x4 v4 = __builtin_nontemporal_load((const i32x4*)(pn + idx));
#pragma unroll
    for (int j = 0; j < 4; j++) {
      atomicAdd(&ce[e4[j] / EPB], 1);
      atomicAdd(&cn[v4[j] / NPB], 1);
    }
  }
  __syncthreads();
  for (int i = t; i < NB; i += 256) {
    ce[i] = atomicAdd(&gcure[i], ce[i]);
    cn[i] = atomicAdd(&gcurn[i], cn[i]);
  }
  __syncthreads();
  for (int q = t; q < PA_CHUNK / 4; q += 256) {
    long long idx = base + (long long)q * 4;
    if (idx >= N_PAIRSC) break;
    i32x4 e4 = __builtin_nontemporal_load((const i32x4*)(pe + idx));
    i32x4 v4 = __builtin_nontemporal_load((const i32x4*)(pn + idx));
#pragma unroll
    for (int j = 0; j < 4; j++) {
      unsigned ee = (unsigned)e4[j], vv = (unsigned)v4[j];
      int p1 = atomicAdd(&ce[ee / EPB], 1);
      buckE[p1] = (ee << 17) | vv;          // edge key (14b) | node val (17b)
      int p2 = atomicAdd(&cn[vv / NPB], 1);
      buckN[p2] = (vv << 14) | ee;          // node key (17b) | edge val (14b)
    }
  }
}

// ---------------- phase B: fine scatter + per-key counts/offsets from bucket ----------------
__global__ __launch_bounds__(256) void k_fine(const unsigned* __restrict__ buckE,
                                              const unsigned* __restrict__ buckN,
                                              const int* __restrict__ ebase, const int* __restrict__ nbase,
                                              int* __restrict__ ecnt, int* __restrict__ eoff,
                                              int* __restrict__ ncnt, int* __restrict__ noff,
                                              int* __restrict__ sn, int* __restrict__ se) {
  __shared__ int cnt_s[NPB], cur_s[NPB];
  int b = blockIdx.x, t = threadIdx.x;
  const unsigned* buck;
  int *kcnt, *koff, *out;
  int keys, lo, beg, end, shift, mask;
  if (b < NB) {
    buck = buckE; kcnt = ecnt; koff = eoff; out = sn;
    keys = EPB; lo = b * EPB; beg = ebase[b]; end = ebase[b + 1];
    shift = 17; mask = 0x1FFFF;
  } else {
    int bb = b - NB;
    buck = buckN; kcnt = ncnt; koff = noff; out = se;
    keys = NPB; lo = bb * NPB; beg = nbase[bb]; end = nbase[bb + 1];
    shift = 14; mask = 0x3FFF;
  }
  for (int i = t; i < keys; i += 256) cnt_s[i] = 0;
  __syncthreads();
  for (int i = beg + t; i < end; i += 256) {
    int key = (int)(buck[i] >> shift) - lo;
    atomicAdd(&cnt_s[key], 1);
  }
  __syncthreads();
  if (t < 64) {
    int carry = beg;
    for (int base = 0; base < keys; base += 64) {
      int idx = base + t;
      int v = (idx < keys) ? cnt_s[idx] : 0;
      int inc = wave_incl_scan(v, t);
      if (idx < keys) cur_s[idx] = carry + inc - v;
      carry += __shfl(inc, 63, 64);
    }
  }
  __syncthreads();
  for (int i = t; i < keys; i += 256) {
    kcnt[lo + i] = cnt_s[i];
    koff[lo + i] = cur_s[i];
  }
  __syncthreads();
  for (int i = beg + t; i < end; i += 256) {
    unsigned u = buck[i];
    int key = (int)(u >> shift) - lo;
    int val = (int)(u & mask);
    int pos = atomicAdd(&cur_s[key], 1);
    out[pos] = val;
  }
}

// ---------------- GEMM 1: m_ji = gelu(x @ Wmsg^T) * send  -> fp8 e4m3 ----------------
__global__ __launch_bounds__(256) void k_gemm_msg(const short* __restrict__ xb, const short* __restrict__ wb,
                                                  const float* __restrict__ send,
                                                  unsigned char* __restrict__ mji8) {
  int gw = (blockIdx.x * 256 + threadIdx.x) >> 6;
  int lane = threadIdx.x & 63;
  int rb = gw * 16;
  if (rb >= N_NODESC) return;
  int lr = lane & 15, lg = lane >> 4;

  bf16x8 A[4];
  const short* xrow = xb + (size_t)(rb + lr) * FDIM + lg * 8;
#pragma unroll
  for (int kk = 0; kk < 4; kk++) A[kk] = *(const bf16x8*)(xrow + kk * 32);

  float sv[4];
#pragma unroll
  for (int j = 0; j < 4; j++) sv[j] = send[rb + lg * 4 + j];

#pragma unroll
  for (int c = 0; c < 8; c++) {
    f32x4 acc = {0.f, 0.f, 0.f, 0.f};
    const short* wrow = wb + (size_t)(16 * c + lr) * FDIM + lg * 8;
#pragma unroll
    for (int kk = 0; kk < 4; kk++) {
      bf16x8 B = *(const bf16x8*)(wrow + kk * 32);
      acc = __builtin_amdgcn_mfma_f32_16x16x32_bf16(A[kk], B, acc, 0, 0, 0);
    }
#pragma unroll
    for (int j = 0; j < 4; j++) {
      float z = acc[j];
      float m = gelu_exact(z) * sv[j];
      int row = rb + lg * 4 + j, col = 16 * c + lr;
      int pk = __builtin_amdgcn_cvt_pk_fp8_f32(m, m, 0, false);
      mji8[(size_t)row * FDIM + col] = (unsigned char)(pk & 0xFF);
    }
  }
}

// ---------------- edge reduce: 4 pairs/wave, 16 lanes x 8B fp8 per row ----------------
__global__ __launch_bounds__(256) void k_edge(const unsigned char* __restrict__ mji8, const int* __restrict__ sn,
                                              const int* __restrict__ eoff, const int* __restrict__ ecnt,
                                              unsigned char* __restrict__ efeat8) {
  int wv = blockIdx.x * 4 + (threadIdx.x >> 6);
  int lane = threadIdx.x & 63;
  if (wv >= N_EDGESC) return;
  int beg = eoff[wv], cnt = ecnt[wv];
  int sub = lane >> 4, c4 = lane & 15;
  float a0 = 0.f, a1 = 0.f, a2 = 0.f, a3 = 0.f;
  float a4 = 0.f, a5 = 0.f, a6 = 0.f, a7 = 0.f;
#pragma unroll 4
  for (int p = sub; p < cnt; p += 4) {
    int node = sn[beg + p];
    uint2 u = ((const uint2*)(mji8 + (size_t)node * FDIM))[c4];
    f32x2 f0 = __builtin_amdgcn_cvt_pk_f32_fp8(u.x, false);
    f32x2 f1 = __builtin_amdgcn_cvt_pk_f32_fp8(u.x, true);
    f32x2 f2 = __builtin_amdgcn_cvt_pk_f32_fp8(u.y, false);
    f32x2 f3 = __builtin_amdgcn_cvt_pk_f32_fp8(u.y, true);
    a0 += f0[0]; a1 += f0[1]; a2 += f1[0]; a3 += f1[1];
    a4 += f2[0]; a5 += f2[1]; a6 += f3[0]; a7 += f3[1];
  }
#pragma unroll
  for (int d = 16; d <= 32; d <<= 1) {
    a0 += __shfl_xor(a0, d, 64); a1 += __shfl_xor(a1, d, 64);
    a2 += __shfl_xor(a2, d, 64); a3 += __shfl_xor(a3, d, 64);
    a4 += __shfl_xor(a4, d, 64); a5 += __shfl_xor(a5, d, 64);
    a6 += __shfl_xor(a6, d, 64); a7 += __shfl_xor(a7, d, 64);
  }
  if (sub == 0) {
    float inv = 1.0f / fmaxf((float)cnt, 1.0f);
    uint2 o;
    o.x = (unsigned)__builtin_amdgcn_cvt_pk_fp8_f32(a0 * inv, a1 * inv, 0, false);
    o.x = (unsigned)__builtin_amdgcn_cvt_pk_fp8_f32(a2 * inv, a3 * inv, (int)o.x, true);
    o.y = (unsigned)__builtin_amdgcn_cvt_pk_fp8_f32(a4 * inv, a5 * inv, 0, false);
    o.y = (unsigned)__builtin_amdgcn_cvt_pk_fp8_f32(a6 * inv, a7 * inv, (int)o.y, true);
    ((uint2*)(efeat8 + (size_t)wv * FDIM))[c4] = o;
  }
}

// ---------------- node reduce: 4 pairs/wave, 16 lanes x 8B fp8 per row -> bf16 mi ----------------
__global__ __launch_bounds__(256) void k_node(const unsigned char* __restrict__ efeat8, const int* __restrict__ se,
                                              const int* __restrict__ noff, const int* __restrict__ ncnt,
                                              const float* __restrict__ recv, short* __restrict__ mi) {
  int wv = blockIdx.x * 4 + (threadIdx.x >> 6);
  int lane = threadIdx.x & 63;
  if (wv >= N_NODESC) return;
  int beg = noff[wv], cnt = ncnt[wv];
  int sub = lane >> 4, c4 = lane & 15;
  float a0 = 0.f, a1 = 0.f, a2 = 0.f, a3 = 0.f;
  float a4 = 0.f, a5 = 0.f, a6 = 0.f, a7 = 0.f;
#pragma unroll 4
  for (int p = sub; p < cnt; p += 4) {
    int e = se[beg + p];
    uint2 u = ((const uint2*)(efeat8 + (size_t)e * FDIM))[c4];
    f32x2 f0 = __builtin_amdgcn_cvt_pk_f32_fp8(u.x, false);
    f32x2 f1 = __builtin_amdgcn_cvt_pk_f32_fp8(u.x, true);
    f32x2 f2 = __builtin_amdgcn_cvt_pk_f32_fp8(u.y, false);
    f32x2 f3 = __builtin_amdgcn_cvt_pk_f32_fp8(u.y, true);
    a0 += f0[0]; a1 += f0[1]; a2 += f1[0]; a3 += f1[1];
    a4 += f2[0]; a5 += f2[1]; a6 += f3[0]; a7 += f3[1];
  }
#pragma unroll
  for (int d = 16; d <= 32; d <<= 1) {
    a0 += __shfl_xor(a0, d, 64); a1 += __shfl_xor(a1, d, 64);
    a2 += __shfl_xor(a2, d, 64); a3 += __shfl_xor(a3, d, 64);
    a4 += __shfl_xor(a4, d, 64); a5 += __shfl_xor(a5, d, 64);
    a6 += __shfl_xor(a6, d, 64); a7 += __shfl_xor(a7, d, 64);
  }
  if (sub == 0) {
    float s = recv[wv] / fmaxf((float)cnt, 1.0f);
    u32x4 o;
    o[0] = pack2(a0 * s, a1 * s);
    o[1] = pack2(a2 * s, a3 * s);
    o[2] = pack2(a4 * s, a5 * s);
    o[3] = pack2(a6 * s, a7 * s);
    ((u32x4*)(mi + (size_t)wv * FDIM))[c4] = o;
  }
}

// ---------------- GEMM 2: out = gelu(x @ Wupd^T + b + m_i)  -> f32 ----------------
__global__ __launch_bounds__(256) void k_gemm_upd(const short* __restrict__ xb, const short* __restrict__ wb,
                                                  const float* __restrict__ bias, const short* __restrict__ mi,
                                                  float* __restrict__ out) {
  int gw = (blockIdx.x * 256 + threadIdx.x) >> 6;
  int lane = threadIdx.x & 63;
  int rb = gw * 16;
  if (rb >= N_NODESC) return;
  int lr = lane & 15, lg = lane >> 4;

  bf16x8 A[4];
  const short* xrow = xb + (size_t)(rb + lr) * FDIM + lg * 8;
#pragma unroll
  for (int kk = 0; kk < 4; kk++) A[kk] = *(const bf16x8*)(xrow + kk * 32);

#pragma unroll
  for (int c = 0; c < 8; c++) {
    f32x4 acc = {0.f, 0.f, 0.f, 0.f};
    const short* wrow = wb + (size_t)(16 * c + lr) * FDIM + lg * 8;
#pragma unroll
    for (int kk = 0; kk < 4; kk++) {
      bf16x8 B = *(const bf16x8*)(wrow + kk * 32);
      acc = __builtin_amdgcn_mfma_f32_16x16x32_bf16(A[kk], B, acc, 0, 0, 0);
    }
    int col = 16 * c + lr;
    float bc = bias[col];
#pragma unroll
    for (int j = 0; j < 4; j++) {
      int row = rb + lg * 4 + j;
      float z = acc[j] + bc + b2f(((const unsigned short*)mi)[(size_t)row * FDIM + col]);
      out[(size_t)row * FDIM + col] = gelu_exact(z);
    }
  }
}

extern "C" void kernel_launch(void* const* d_in, const int* in_sizes, int n_in,
                              void* d_out, int out_size, void* d_ws, size_t ws_size,
                              hipStream_t stream) {
  const float* x = (const float*)d_in[0];
  const float* action = (const float*)d_in[1];
  const float* wmsg = (const float*)d_in[2];
  const float* wupd = (const float*)d_in[3];
  const float* bupd = (const float*)d_in[4];
  const int* pn = (const int*)d_in[5];
  const int* pe = (const int*)d_in[6];
  float* out = (float*)d_out;

  char* p = (char*)d_ws;
  auto alloc = [&](size_t bytes) -> char* {
    char* r = p;
    p += (bytes + 255) & ~(size_t)255;
    return r;
  };
  short* xb = (short*)alloc((size_t)N_NODESC * FDIM * 2);
  unsigned char* mji8 = (unsigned char*)alloc((size_t)N_NODESC * FDIM);
  short* mi = (short*)alloc((size_t)N_NODESC * FDIM * 2);   // also hosts buckE+buckN (consumed before k_node writes mi)
  unsigned char* efeat8 = (unsigned char*)alloc((size_t)N_EDGESC * FDIM);
  int* sn = (int*)alloc((size_t)N_PAIRSC * 4);
  int* se = (int*)alloc((size_t)N_PAIRSC * 4);
  short* wmsgb = (short*)alloc(FDIM * FDIM * 2);
  short* wupdb = (short*)alloc(FDIM * FDIM * 2);
  float* send = (float*)alloc(N_NODESC * 4);
  float* recv = (float*)alloc(N_NODESC * 4);
  int* ecnt = (int*)alloc(N_EDGESC * 4);
  int* eoff = (int*)alloc(N_EDGESC * 4);
  int* ncnt = (int*)alloc(N_NODESC * 4);
  int* noff = (int*)alloc(N_NODESC * 4);
  int* part = (int*)alloc((size_t)BH_BLOCKS * 2 * NB * 4);
  int* ebase = (int*)alloc((NB + 1) * 4);
  int* nbase = (int*)alloc((NB + 1) * 4);
  int* gcure = (int*)alloc(NB * 4);
  int* gcurn = (int*)alloc(NB * 4);

  unsigned* buckE = (unsigned*)mi;                      // 6.4 MB
  unsigned* buckN = buckE + (size_t)N_PAIRSC;           // 6.4 MB (fits mi's 25.6 MB region)

  k_prep<<<12500, 256, 0, stream>>>(x, action, wmsg, wupd, xb, wmsgb, wupdb, send, recv);
  k_bhist<<<BH_BLOCKS, 256, 0, stream>>>(pn, pe, part);
  k_bscan<<<1, 256, 0, stream>>>(part, ebase, nbase, gcure, gcurn);
  k_part<<<PA_NCH, 256, 0, stream>>>(pn, pe, gcure, gcurn, buckE, buckN);
  k_fine<<<2 * NB, 256, 0, stream>>>(buckE, buckN, ebase, nbase, ecnt, eoff, ncnt, noff, sn, se);
  k_gemm_msg<<<1563, 256, 0, stream>>>(xb, wmsgb, send, mji8);
  k_edge<<<2500, 256, 0, stream>>>(mji8, sn, eoff, ecnt, efeat8);
  k_node<<<25000, 256, 0, stream>>>(efeat8, se, noff, ncnt, recv, mi);
  k_gemm_upd<<<1563, 256, 0, stream>>>(xb, wupdb, bupd, mi, out);
}

// Round 9
// 230.750 us; speedup vs baseline: 2.7247x; 1.0894x over previous
//
#include <hip/hip_runtime.h>

#define N_NODESC 100000
#define N_EDGESC 10000
#define N_PAIRSC 1600000
#define FDIM 128

#define NB 200       // buckets per path
#define EPB 50       // edges per bucket  (200*50 = 10000)
#define NPB 500      // nodes per bucket  (200*500 = 100000)
#define PA_CHUNK 8192
#define PA_NCH ((N_PAIRSC + PA_CHUNK - 1) / PA_CHUNK)  // 196

#define BH_BLOCKS 250
#define BH_CHUNK 6400   // 250 * 6400 = 1.6M exactly

typedef short bf16x8 __attribute__((ext_vector_type(8)));
typedef float f32x4 __attribute__((ext_vector_type(4)));
typedef float f32x2 __attribute__((ext_vector_type(2)));
typedef int i32x4 __attribute__((ext_vector_type(4)));
typedef unsigned u32x4 __attribute__((ext_vector_type(4)));

__device__ __forceinline__ unsigned short f2b(float f) {
  unsigned u = __float_as_uint(f);
  u += 0x7fffu + ((u >> 16) & 1u);
  return (unsigned short)(u >> 16);
}
__device__ __forceinline__ float b2f(unsigned short b) {
  return __uint_as_float(((unsigned)b) << 16);
}
__device__ __forceinline__ unsigned pack2(float a, float b) {
  return (unsigned)f2b(a) | ((unsigned)f2b(b) << 16);
}
__device__ __forceinline__ float gelu_exact(float z) {
  return 0.5f * z * (1.0f + erff(z * 0.70710678118f));
}

// ---------------- prep: pure streaming bf16 convert + send/recv ----------------
__global__ __launch_bounds__(256) void k_prep(const float* __restrict__ x, const float* __restrict__ action,
                                              const float* __restrict__ wmsg, const float* __restrict__ wupd,
                                              short* __restrict__ xb, short* __restrict__ wmsgb,
                                              short* __restrict__ wupdb, float* __restrict__ send,
                                              float* __restrict__ recv) {
  int i = blockIdx.x * 256 + threadIdx.x;
  if (i < (N_NODESC * FDIM) / 4) {
    const float4 v = ((const float4*)x)[i];
    uint2 o;
    o.x = pack2(v.x, v.y);
    o.y = pack2(v.z, v.w);
    ((uint2*)xb)[i] = o;
  }
  if (i < FDIM * FDIM) {
    wmsgb[i] = (short)f2b(wmsg[i]);
    wupdb[i] = (short)f2b(wupd[i]);
  }
  if (i < N_NODESC) {
    float a0 = action[i * 3 + 0], a1 = action[i * 3 + 1], a2 = action[i * 3 + 2];
    send[i] = a0 + a2;
    recv[i] = a0 + a1;
  }
}

// ---------------- bucket histogram: per-block LDS 400 bins -> coalesced partials ----------------
__global__ __launch_bounds__(256) void k_bhist(const int* __restrict__ pn, const int* __restrict__ pe,
                                               int* __restrict__ part) {
  __shared__ int h[2 * NB];
  int t = threadIdx.x;
  for (int i = t; i < 2 * NB; i += 256) h[i] = 0;
  __syncthreads();
  int base = blockIdx.x * BH_CHUNK;
  for (int q = t; q < BH_CHUNK / 4; q += 256) {
    int idx = base + q * 4;
    i32x4 e4 = __builtin_nontemporal_load((const i32x4*)(pe + idx));
    i32x4 v4 = __builtin_nontemporal_load((const i32x4*)(pn + idx));
#pragma unroll
    for (int j = 0; j < 4; j++) {
      atomicAdd(&h[e4[j] / EPB], 1);
      atomicAdd(&h[NB + v4[j] / NPB], 1);
    }
  }
  __syncthreads();
  for (int i = t; i < 2 * NB; i += 256) part[blockIdx.x * 2 * NB + i] = h[i];
}

// ---------------- scan helper ----------------
__device__ __forceinline__ int wave_incl_scan(int v, int lane) {
#pragma unroll
  for (int d = 1; d < 64; d <<= 1) {
    int n = __shfl_up(v, d, 64);
    if (lane >= d) v += n;
  }
  return v;
}

// ---------------- reduce partials + scan bucket bases + init cursors ----------------
__global__ __launch_bounds__(256) void k_bscan(const int* __restrict__ part, int* __restrict__ ebase,
                                               int* __restrict__ nbase, int* __restrict__ gcure,
                                               int* __restrict__ gcurn) {
  __shared__ int tot[2 * NB];
  int t = threadIdx.x;
  for (int i = t; i < 2 * NB; i += 256) {
    int s = 0;
    for (int b = 0; b < BH_BLOCKS; b++) s += part[b * 2 * NB + i];
    tot[i] = s;
  }
  __syncthreads();
  if (t < 64) {
    int carry = 0;
    for (int base = 0; base < NB; base += 64) {
      int idx = base + t;
      int v = (idx < NB) ? tot[idx] : 0;
      int inc = wave_incl_scan(v, t);
      if (idx < NB) { ebase[idx] = carry + inc - v; gcure[idx] = carry + inc - v; }
      carry += __shfl(inc, 63, 64);
    }
    if (t == 0) ebase[NB] = N_PAIRSC;
  } else if (t < 128) {
    int lane = t - 64;
    int carry = 0;
    for (int base = 0; base < NB; base += 64) {
      int idx = base + lane;
      int v = (idx < NB) ? tot[NB + idx] : 0;
      int inc = wave_incl_scan(v, lane);
      if (idx < NB) { nbase[idx] = carry + inc - v; gcurn[idx] = carry + inc - v; }
      carry += __shfl(inc, 63, 64);
    }
    if (lane == 0) nbase[NB] = N_PAIRSC;
  }
}

// ---------------- phase A: coarse bucket partition (31-bit packed items) ----------------
__global__ __launch_bounds__(256) void k_part(const int* __restrict__ pn, const int* __restrict__ pe,
                                              int* __restrict__ gcure, int* __restrict__ gcurn,
                                              unsigned* __restrict__ buckE,
                                              unsigned* __restrict__ buckN) {
  __shared__ int ce[NB], cn[NB];
  int t = threadIdx.x;
  for (int i = t; i < NB; i += 256) { ce[i] = 0; cn[i] = 0; }
  __syncthreads();
  long long base = (long long)blockIdx.x * PA_CHUNK;
  for (int q = t; q < PA_CHUNK / 4; q += 256) {
    long long idx = base + (long long)q * 4;
    if (idx >= N_PAIRSC) break;
    i32x4 e4 = __builtin_nontemporal_load((const i32x4*)(pe + idx));
    i32x4 v4 = __builtin_nontemporal_load((const i32x4*)(pn + idx));
#pragma unroll
    for (int j = 0; j < 4; j++) {
      atomicAdd(&ce[e4[j] / EPB], 1);
      atomicAdd(&cn[v4[j] / NPB], 1);
    }
  }
  __syncthreads();
  for (int i = t; i < NB; i += 256) {
    ce[i] = atomicAdd(&gcure[i], ce[i]);
    cn[i] = atomicAdd(&gcurn[i], cn[i]);
  }
  __syncthreads();
  for (int q = t; q < PA_CHUNK / 4; q += 256) {
    long long idx = base + (long long)q * 4;
    if (idx >= N_PAIRSC) break;
    i32x4 e4 = __builtin_nontemporal_load((const i32x4*)(pe + idx));
    i32x4 v4 = __builtin_nontemporal_load((const i32x4*)(pn + idx));
#pragma unroll
    for (int j = 0; j < 4; j++) {
      unsigned ee = (unsigned)e4[j], vv = (unsigned)v4[j];
      int p1 = atomicAdd(&ce[ee / EPB], 1);
      buckE[p1] = (ee << 17) | vv;          // edge key (14b) | node val (17b)
      int p2 = atomicAdd(&cn[vv / NPB], 1);
      buckN[p2] = (vv << 14) | ee;          // node key (17b) | edge val (14b)
    }
  }
}

// ---------------- phase B: fine scatter + per-key counts/offsets from bucket ----------------
__global__ __launch_bounds__(256) void k_fine(const unsigned* __restrict__ buckE,
                                              const unsigned* __restrict__ buckN,
                                              const int* __restrict__ ebase, const int* __restrict__ nbase,
                                              int* __restrict__ ecnt, int* __restrict__ eoff,
                                              int* __restrict__ ncnt, int* __restrict__ noff,
                                              int* __restrict__ sn, int* __restrict__ se) {
  __shared__ int cnt_s[NPB], cur_s[NPB];
  int b = blockIdx.x, t = threadIdx.x;
  const unsigned* buck;
  int *kcnt, *koff, *out;
  int keys, lo, beg, end, shift, mask;
  if (b < NB) {
    buck = buckE; kcnt = ecnt; koff = eoff; out = sn;
    keys = EPB; lo = b * EPB; beg = ebase[b]; end = ebase[b + 1];
    shift = 17; mask = 0x1FFFF;
  } else {
    int bb = b - NB;
    buck = buckN; kcnt = ncnt; koff = noff; out = se;
    keys = NPB; lo = bb * NPB; beg = nbase[bb]; end = nbase[bb + 1];
    shift = 14; mask = 0x3FFF;
  }
  for (int i = t; i < keys; i += 256) cnt_s[i] = 0;
  __syncthreads();
  for (int i = beg + t; i < end; i += 256) {
    int key = (int)(buck[i] >> shift) - lo;
    atomicAdd(&cnt_s[key], 1);
  }
  __syncthreads();
  if (t < 64) {
    int carry = beg;
    for (int base = 0; base < keys; base += 64) {
      int idx = base + t;
      int v = (idx < keys) ? cnt_s[idx] : 0;
      int inc = wave_incl_scan(v, t);
      if (idx < keys) cur_s[idx] = carry + inc - v;
      carry += __shfl(inc, 63, 64);
    }
  }
  __syncthreads();
  for (int i = t; i < keys; i += 256) {
    kcnt[lo + i] = cnt_s[i];
    koff[lo + i] = cur_s[i];
  }
  __syncthreads();
  for (int i = beg + t; i < end; i += 256) {
    unsigned u = buck[i];
    int key = (int)(u >> shift) - lo;
    int val = (int)(u & mask);
    int pos = atomicAdd(&cur_s[key], 1);
    out[pos] = val;
  }
}

// ---------------- GEMM 1: m_ji = gelu(x @ Wmsg^T) * send  -> fp8 e4m3 ----------------
__global__ __launch_bounds__(256) void k_gemm_msg(const short* __restrict__ xb, const short* __restrict__ wb,
                                                  const float* __restrict__ send,
                                                  unsigned char* __restrict__ mji8) {
  int gw = (blockIdx.x * 256 + threadIdx.x) >> 6;
  int lane = threadIdx.x & 63;
  int rb = gw * 16;
  if (rb >= N_NODESC) return;
  int lr = lane & 15, lg = lane >> 4;

  bf16x8 A[4];
  const short* xrow = xb + (size_t)(rb + lr) * FDIM + lg * 8;
#pragma unroll
  for (int kk = 0; kk < 4; kk++) A[kk] = *(const bf16x8*)(xrow + kk * 32);

  float sv[4];
#pragma unroll
  for (int j = 0; j < 4; j++) sv[j] = send[rb + lg * 4 + j];

#pragma unroll
  for (int c = 0; c < 8; c++) {
    f32x4 acc = {0.f, 0.f, 0.f, 0.f};
    const short* wrow = wb + (size_t)(16 * c + lr) * FDIM + lg * 8;
#pragma unroll
    for (int kk = 0; kk < 4; kk++) {
      bf16x8 B = *(const bf16x8*)(wrow + kk * 32);
      acc = __builtin_amdgcn_mfma_f32_16x16x32_bf16(A[kk], B, acc, 0, 0, 0);
    }
#pragma unroll
    for (int j = 0; j < 4; j++) {
      float z = acc[j];
      float m = gelu_exact(z) * sv[j];
      int row = rb + lg * 4 + j, col = 16 * c + lr;
      int pk = __builtin_amdgcn_cvt_pk_fp8_f32(m, m, 0, false);
      mji8[(size_t)row * FDIM + col] = (unsigned char)(pk & 0xFF);
    }
  }
}

// ---------------- edge reduce: 2 edges/wave, 2 subs per edge, packed f32x2 acc ----------------
__global__ __launch_bounds__(256) void k_edge(const unsigned char* __restrict__ mji8, const int* __restrict__ sn,
                                              const int* __restrict__ eoff, const int* __restrict__ ecnt,
                                              unsigned char* __restrict__ efeat8) {
  int wave = blockIdx.x * 4 + (threadIdx.x >> 6);
  int lane = threadIdx.x & 63;
  int half = lane >> 5;          // which edge of the 2
  int sub2 = (lane >> 4) & 1;    // which pair-interleave within the edge
  int c4 = lane & 15;
  int edge = wave * 2 + half;
  if (edge >= N_EDGESC) return;
  int beg = eoff[edge], cnt = ecnt[edge];
  f32x2 a0 = {0.f, 0.f}, a1 = {0.f, 0.f}, a2 = {0.f, 0.f}, a3 = {0.f, 0.f};
#pragma unroll 4
  for (int p = sub2; p < cnt; p += 2) {
    int node = sn[beg + p];
    uint2 u = ((const uint2*)(mji8 + (size_t)node * FDIM))[c4];
    a0 += __builtin_amdgcn_cvt_pk_f32_fp8(u.x, false);
    a1 += __builtin_amdgcn_cvt_pk_f32_fp8(u.x, true);
    a2 += __builtin_amdgcn_cvt_pk_f32_fp8(u.y, false);
    a3 += __builtin_amdgcn_cvt_pk_f32_fp8(u.y, true);
  }
  // combine the two pair-interleaves (lanes ^16 within each 32-lane half)
  a0[0] += __shfl_xor(a0[0], 16, 64); a0[1] += __shfl_xor(a0[1], 16, 64);
  a1[0] += __shfl_xor(a1[0], 16, 64); a1[1] += __shfl_xor(a1[1], 16, 64);
  a2[0] += __shfl_xor(a2[0], 16, 64); a2[1] += __shfl_xor(a2[1], 16, 64);
  a3[0] += __shfl_xor(a3[0], 16, 64); a3[1] += __shfl_xor(a3[1], 16, 64);
  if (sub2 == 0) {
    float inv = 1.0f / fmaxf((float)cnt, 1.0f);
    uint2 o;
    o.x = (unsigned)__builtin_amdgcn_cvt_pk_fp8_f32(a0[0] * inv, a0[1] * inv, 0, false);
    o.x = (unsigned)__builtin_amdgcn_cvt_pk_fp8_f32(a1[0] * inv, a1[1] * inv, (int)o.x, true);
    o.y = (unsigned)__builtin_amdgcn_cvt_pk_fp8_f32(a2[0] * inv, a2[1] * inv, 0, false);
    o.y = (unsigned)__builtin_amdgcn_cvt_pk_fp8_f32(a3[0] * inv, a3[1] * inv, (int)o.y, true);
    ((uint2*)(efeat8 + (size_t)edge * FDIM))[c4] = o;
  }
}

// ---------------- node reduce: one node per 16-lane sub (4 nodes/wave), no shuffle epilogue ----------------
__global__ __launch_bounds__(256) void k_node(const unsigned char* __restrict__ efeat8, const int* __restrict__ se,
                                              const int* __restrict__ noff, const int* __restrict__ ncnt,
                                              const float* __restrict__ recv, short* __restrict__ mi) {
  int wave = blockIdx.x * 4 + (threadIdx.x >> 6);
  int lane = threadIdx.x & 63;
  int sub = lane >> 4, c4 = lane & 15;
  int node = wave * 4 + sub;   // 25000 waves x 4 = 100000 exactly
  int beg = noff[node], cnt = ncnt[node];
  f32x2 a0 = {0.f, 0.f}, a1 = {0.f, 0.f}, a2 = {0.f, 0.f}, a3 = {0.f, 0.f};
#pragma unroll 4
  for (int p = 0; p < cnt; p++) {
    int e = se[beg + p];
    uint2 u = ((const uint2*)(efeat8 + (size_t)e * FDIM))[c4];
    a0 += __builtin_amdgcn_cvt_pk_f32_fp8(u.x, false);
    a1 += __builtin_amdgcn_cvt_pk_f32_fp8(u.x, true);
    a2 += __builtin_amdgcn_cvt_pk_f32_fp8(u.y, false);
    a3 += __builtin_amdgcn_cvt_pk_f32_fp8(u.y, true);
  }
  float s = recv[node] / fmaxf((float)cnt, 1.0f);
  u32x4 o;
  o[0] = pack2(a0[0] * s, a0[1] * s);
  o[1] = pack2(a1[0] * s, a1[1] * s);
  o[2] = pack2(a2[0] * s, a2[1] * s);
  o[3] = pack2(a3[0] * s, a3[1] * s);
  ((u32x4*)(mi + (size_t)node * FDIM))[c4] = o;
}

// ---------------- GEMM 2: out = gelu(x @ Wupd^T + b + m_i)  -> f32 ----------------
__global__ __launch_bounds__(256) void k_gemm_upd(const short* __restrict__ xb, const short* __restrict__ wb,
                                                  const float* __restrict__ bias, const short* __restrict__ mi,
                                                  float* __restrict__ out) {
  int gw = (blockIdx.x * 256 + threadIdx.x) >> 6;
  int lane = threadIdx.x & 63;
  int rb = gw * 16;
  if (rb >= N_NODESC) return;
  int lr = lane & 15, lg = lane >> 4;

  bf16x8 A[4];
  const short* xrow = xb + (size_t)(rb + lr) * FDIM + lg * 8;
#pragma unroll
  for (int kk = 0; kk < 4; kk++) A[kk] = *(const bf16x8*)(xrow + kk * 32);

#pragma unroll
  for (int c = 0; c < 8; c++) {
    f32x4 acc = {0.f, 0.f, 0.f, 0.f};
    const short* wrow = wb + (size_t)(16 * c + lr) * FDIM + lg * 8;
#pragma unroll
    for (int kk = 0; kk < 4; kk++) {
      bf16x8 B = *(const bf16x8*)(wrow + kk * 32);
      acc = __builtin_amdgcn_mfma_f32_16x16x32_bf16(A[kk], B, acc, 0, 0, 0);
    }
    int col = 16 * c + lr;
    float bc = bias[col];
#pragma unroll
    for (int j = 0; j < 4; j++) {
      int row = rb + lg * 4 + j;
      float z = acc[j] + bc + b2f(((const unsigned short*)mi)[(size_t)row * FDIM + col]);
      out[(size_t)row * FDIM + col] = gelu_exact(z);
    }
  }
}

extern "C" void kernel_launch(void* const* d_in, const int* in_sizes, int n_in,
                              void* d_out, int out_size, void* d_ws, size_t ws_size,
                              hipStream_t stream) {
  const float* x = (const float*)d_in[0];
  const float* action = (const float*)d_in[1];
  const float* wmsg = (const float*)d_in[2];
  const float* wupd = (const float*)d_in[3];
  const float* bupd = (const float*)d_in[4];
  const int* pn = (const int*)d_in[5];
  const int* pe = (const int*)d_in[6];
  float* out = (float*)d_out;

  char* p = (char*)d_ws;
  auto alloc = [&](size_t bytes) -> char* {
    char* r = p;
    p += (bytes + 255) & ~(size_t)255;
    return r;
  };
  short* xb = (short*)alloc((size_t)N_NODESC * FDIM * 2);
  unsigned char* mji8 = (unsigned char*)alloc((size_t)N_NODESC * FDIM);
  short* mi = (short*)alloc((size_t)N_NODESC * FDIM * 2);   // also hosts buckE+buckN (consumed before k_node writes mi)
  unsigned char* efeat8 = (unsigned char*)alloc((size_t)N_EDGESC * FDIM);
  int* sn = (int*)alloc((size_t)N_PAIRSC * 4);
  int* se = (int*)alloc((size_t)N_PAIRSC * 4);
  short* wmsgb = (short*)alloc(FDIM * FDIM * 2);
  short* wupdb = (short*)alloc(FDIM * FDIM * 2);
  float* send = (float*)alloc(N_NODESC * 4);
  float* recv = (float*)alloc(N_NODESC * 4);
  int* ecnt = (int*)alloc(N_EDGESC * 4);
  int* eoff = (int*)alloc(N_EDGESC * 4);
  int* ncnt = (int*)alloc(N_NODESC * 4);
  int* noff = (int*)alloc(N_NODESC * 4);
  int* part = (int*)alloc((size_t)BH_BLOCKS * 2 * NB * 4);
  int* ebase = (int*)alloc((NB + 1) * 4);
  int* nbase = (int*)alloc((NB + 1) * 4);
  int* gcure = (int*)alloc(NB * 4);
  int* gcurn = (int*)alloc(NB * 4);

  unsigned* buckE = (unsigned*)mi;                      // 6.4 MB
  unsigned* buckN = buckE + (size_t)N_PAIRSC;           // 6.4 MB (fits mi's 25.6 MB region)

  k_prep<<<12500, 256, 0, stream>>>(x, action, wmsg, wupd, xb, wmsgb, wupdb, send, recv);
  k_bhist<<<BH_BLOCKS, 256, 0, stream>>>(pn, pe, part);
  k_bscan<<<1, 256, 0, stream>>>(part, ebase, nbase, gcure, gcurn);
  k_part<<<PA_NCH, 256, 0, stream>>>(pn, pe, gcure, gcurn, buckE, buckN);
  k_fine<<<2 * NB, 256, 0, stream>>>(buckE, buckN, ebase, nbase, ecnt, eoff, ncnt, noff, sn, se);
  k_gemm_msg<<<1563, 256, 0, stream>>>(xb, wmsgb, send, mji8);
  k_edge<<<1250, 256, 0, stream>>>(mji8, sn, eoff, ecnt, efeat8);
  k_node<<<6250, 256, 0, stream>>>(efeat8, se, noff, ncnt, recv, mi);
  k_gemm_upd<<<1563, 256, 0, stream>>>(xb, wupdb, bupd, mi, out);
}

// Round 10
// 210.759 us; speedup vs baseline: 2.9831x; 1.0949x over previous
//
#include <hip/hip_runtime.h>

#define N_NODESC 100000
#define N_EDGESC 10000
#define N_PAIRSC 1600000
#define FDIM 128

#define NB 200       // buckets per path
#define EPB 50       // edges per bucket  (200*50 = 10000)
#define NPB 500      // nodes per bucket  (200*500 = 100000)
#define PA_CHUNK 8192
#define PA_NCH ((N_PAIRSC + PA_CHUNK - 1) / PA_CHUNK)  // 196

#define BH_BLOCKS 250
#define BH_CHUNK 6400   // 250 * 6400 = 1.6M exactly

typedef short bf16x8 __attribute__((ext_vector_type(8)));
typedef float f32x4 __attribute__((ext_vector_type(4)));
typedef float f32x2 __attribute__((ext_vector_type(2)));
typedef int i32x4 __attribute__((ext_vector_type(4)));
typedef unsigned u32x4 __attribute__((ext_vector_type(4)));

__device__ __forceinline__ unsigned short f2b(float f) {
  unsigned u = __float_as_uint(f);
  u += 0x7fffu + ((u >> 16) & 1u);
  return (unsigned short)(u >> 16);
}
__device__ __forceinline__ float b2f(unsigned short b) {
  return __uint_as_float(((unsigned)b) << 16);
}
__device__ __forceinline__ unsigned pack2(float a, float b) {
  return (unsigned)f2b(a) | ((unsigned)f2b(b) << 16);
}
// tanh-form gelu: z*e/(e+1), e=exp(1.59576912*z*(1+0.044715 z^2)).
// |diff vs erf-gelu| <= ~1e-3, inf-safe (e->inf => z; e->0 => 0). ~9 VALU vs ~27 for erff.
__device__ __forceinline__ float gelu_fast(float z) {
  float z2 = z * z;
  float w = fmaf(0.044715f, z2, 1.0f);
  float e = __expf(1.5957691216f * z * w);
  return z * e * __builtin_amdgcn_rcpf(e + 1.0f);
}

// ---------------- prep: pure streaming bf16 convert + send/recv ----------------
__global__ __launch_bounds__(256) void k_prep(const float* __restrict__ x, const float* __restrict__ action,
                                              const float* __restrict__ wmsg, const float* __restrict__ wupd,
                                              short* __restrict__ xb, short* __restrict__ wmsgb,
                                              short* __restrict__ wupdb, float* __restrict__ send,
                                              float* __restrict__ recv) {
  int i = blockIdx.x * 256 + threadIdx.x;
  if (i < (N_NODESC * FDIM) / 4) {
    const float4 v = ((const float4*)x)[i];
    uint2 o;
    o.x = pack2(v.x, v.y);
    o.y = pack2(v.z, v.w);
    ((uint2*)xb)[i] = o;
  }
  if (i < FDIM * FDIM) {
    wmsgb[i] = (short)f2b(wmsg[i]);
    wupdb[i] = (short)f2b(wupd[i]);
  }
  if (i < N_NODESC) {
    float a0 = action[i * 3 + 0], a1 = action[i * 3 + 1], a2 = action[i * 3 + 2];
    send[i] = a0 + a2;
    recv[i] = a0 + a1;
  }
}

// ---------------- bucket histogram: per-block LDS 400 bins -> coalesced partials ----------------
__global__ __launch_bounds__(256) void k_bhist(const int* __restrict__ pn, const int* __restrict__ pe,
                                               int* __restrict__ part) {
  __shared__ int h[2 * NB];
  int t = threadIdx.x;
  for (int i = t; i < 2 * NB; i += 256) h[i] = 0;
  __syncthreads();
  int base = blockIdx.x * BH_CHUNK;
  for (int q = t; q < BH_CHUNK / 4; q += 256) {
    int idx = base + q * 4;
    i32x4 e4 = __builtin_nontemporal_load((const i32x4*)(pe + idx));
    i32x4 v4 = __builtin_nontemporal_load((const i32x4*)(pn + idx));
#pragma unroll
    for (int j = 0; j < 4; j++) {
      atomicAdd(&h[e4[j] / EPB], 1);
      atomicAdd(&h[NB + v4[j] / NPB], 1);
    }
  }
  __syncthreads();
  for (int i = t; i < 2 * NB; i += 256) part[blockIdx.x * 2 * NB + i] = h[i];
}

// ---------------- scan helper ----------------
__device__ __forceinline__ int wave_incl_scan(int v, int lane) {
#pragma unroll
  for (int d = 1; d < 64; d <<= 1) {
    int n = __shfl_up(v, d, 64);
    if (lane >= d) v += n;
  }
  return v;
}

// ---------------- reduce partials + scan bucket bases + init cursors ----------------
__global__ __launch_bounds__(256) void k_bscan(const int* __restrict__ part, int* __restrict__ ebase,
                                               int* __restrict__ nbase, int* __restrict__ gcure,
                                               int* __restrict__ gcurn) {
  __shared__ int tot[2 * NB];
  int t = threadIdx.x;
  for (int i = t; i < 2 * NB; i += 256) {
    int s = 0;
    for (int b = 0; b < BH_BLOCKS; b++) s += part[b * 2 * NB + i];
    tot[i] = s;
  }
  __syncthreads();
  if (t < 64) {
    int carry = 0;
    for (int base = 0; base < NB; base += 64) {
      int idx = base + t;
      int v = (idx < NB) ? tot[idx] : 0;
      int inc = wave_incl_scan(v, t);
      if (idx < NB) { ebase[idx] = carry + inc - v; gcure[idx] = carry + inc - v; }
      carry += __shfl(inc, 63, 64);
    }
    if (t == 0) ebase[NB] = N_PAIRSC;
  } else if (t < 128) {
    int lane = t - 64;
    int carry = 0;
    for (int base = 0; base < NB; base += 64) {
      int idx = base + lane;
      int v = (idx < NB) ? tot[NB + idx] : 0;
      int inc = wave_incl_scan(v, lane);
      if (idx < NB) { nbase[idx] = carry + inc - v; gcurn[idx] = carry + inc - v; }
      carry += __shfl(inc, 63, 64);
    }
    if (lane == 0) nbase[NB] = N_PAIRSC;
  }
}

// ---------------- phase A: coarse bucket partition (31-bit packed items) ----------------
__global__ __launch_bounds__(256) void k_part(const int* __restrict__ pn, const int* __restrict__ pe,
                                              int* __restrict__ gcure, int* __restrict__ gcurn,
                                              unsigned* __restrict__ buckE,
                                              unsigned* __restrict__ buckN) {
  __shared__ int ce[NB], cn[NB];
  int t = threadIdx.x;
  for (int i = t; i < NB; i += 256) { ce[i] = 0; cn[i] = 0; }
  __syncthreads();
  long long base = (long long)blockIdx.x * PA_CHUNK;
  for (int q = t; q < PA_CHUNK / 4; q += 256) {
    long long idx = base + (long long)q * 4;
    if (idx >= N_PAIRSC) break;
    i32x4 e4 = __builtin_nontemporal_load((const i32x4*)(pe + idx));
    i32x4 v4 = __builtin_nontemporal_load((const i32x4*)(pn + idx));
#pragma unroll
    for (int j = 0; j < 4; j++) {
      atomicAdd(&ce[e4[j] / EPB], 1);
      atomicAdd(&cn[v4[j] / NPB], 1);
    }
  }
  __syncthreads();
  for (int i = t; i < NB; i += 256) {
    ce[i] = atomicAdd(&gcure[i], ce[i]);
    cn[i] = atomicAdd(&gcurn[i], cn[i]);
  }
  __syncthreads();
  for (int q = t; q < PA_CHUNK / 4; q += 256) {
    long long idx = base + (long long)q * 4;
    if (idx >= N_PAIRSC) break;
    i32x4 e4 = __builtin_nontemporal_load((const i32x4*)(pe + idx));
    i32x4 v4 = __builtin_nontemporal_load((const i32x4*)(pn + idx));
#pragma unroll
    for (int j = 0; j < 4; j++) {
      unsigned ee = (unsigned)e4[j], vv = (unsigned)v4[j];
      int p1 = atomicAdd(&ce[ee / EPB], 1);
      buckE[p1] = (ee << 17) | vv;          // edge key (14b) | node val (17b)
      int p2 = atomicAdd(&cn[vv / NPB], 1);
      buckN[p2] = (vv << 14) | ee;          // node key (17b) | edge val (14b)
    }
  }
}

// ---------------- phase B: fine scatter + per-key counts/offsets from bucket ----------------
__global__ __launch_bounds__(256) void k_fine(const unsigned* __restrict__ buckE,
                                              const unsigned* __restrict__ buckN,
                                              const int* __restrict__ ebase, const int* __restrict__ nbase,
                                              int* __restrict__ ecnt, int* __restrict__ eoff,
                                              int* __restrict__ ncnt, int* __restrict__ noff,
                                              int* __restrict__ sn, int* __restrict__ se) {
  __shared__ int cnt_s[NPB], cur_s[NPB];
  int b = blockIdx.x, t = threadIdx.x;
  const unsigned* buck;
  int *kcnt, *koff, *out;
  int keys, lo, beg, end, shift, mask;
  if (b < NB) {
    buck = buckE; kcnt = ecnt; koff = eoff; out = sn;
    keys = EPB; lo = b * EPB; beg = ebase[b]; end = ebase[b + 1];
    shift = 17; mask = 0x1FFFF;
  } else {
    int bb = b - NB;
    buck = buckN; kcnt = ncnt; koff = noff; out = se;
    keys = NPB; lo = bb * NPB; beg = nbase[bb]; end = nbase[bb + 1];
    shift = 14; mask = 0x3FFF;
  }
  for (int i = t; i < keys; i += 256) cnt_s[i] = 0;
  __syncthreads();
  for (int i = beg + t; i < end; i += 256) {
    int key = (int)(buck[i] >> shift) - lo;
    atomicAdd(&cnt_s[key], 1);
  }
  __syncthreads();
  if (t < 64) {
    int carry = beg;
    for (int base = 0; base < keys; base += 64) {
      int idx = base + t;
      int v = (idx < keys) ? cnt_s[idx] : 0;
      int inc = wave_incl_scan(v, t);
      if (idx < keys) cur_s[idx] = carry + inc - v;
      carry += __shfl(inc, 63, 64);
    }
  }
  __syncthreads();
  for (int i = t; i < keys; i += 256) {
    kcnt[lo + i] = cnt_s[i];
    koff[lo + i] = cur_s[i];
  }
  __syncthreads();
  for (int i = beg + t; i < end; i += 256) {
    unsigned u = buck[i];
    int key = (int)(u >> shift) - lo;
    int val = (int)(u & mask);
    int pos = atomicAdd(&cur_s[key], 1);
    out[pos] = val;
  }
}

// ---------------- GEMM 1: m_ji = gelu(x @ Wmsg^T) * send  -> fp8, 32 rows/wave ----------------
__global__ __launch_bounds__(256) void k_gemm_msg(const short* __restrict__ xb, const short* __restrict__ wb,
                                                  const float* __restrict__ send,
                                                  unsigned char* __restrict__ mji8) {
  int gw = (blockIdx.x * 256 + threadIdx.x) >> 6;
  int lane = threadIdx.x & 63;
  if (gw >= N_NODESC / 32) return;
  int rb = gw * 32;
  int lr = lane & 15, lg = lane >> 4;

  bf16x8 A0[4], A1[4];
  const short* xrow0 = xb + (size_t)(rb + lr) * FDIM + lg * 8;
  const short* xrow1 = xrow0 + 16 * FDIM;
#pragma unroll
  for (int kk = 0; kk < 4; kk++) {
    A0[kk] = *(const bf16x8*)(xrow0 + kk * 32);
    A1[kk] = *(const bf16x8*)(xrow1 + kk * 32);
  }

  float sv0[4], sv1[4];
#pragma unroll
  for (int j = 0; j < 4; j++) {
    sv0[j] = send[rb + lg * 4 + j];
    sv1[j] = send[rb + 16 + lg * 4 + j];
  }

#pragma unroll
  for (int c = 0; c < 8; c++) {
    f32x4 acc0 = {0.f, 0.f, 0.f, 0.f}, acc1 = {0.f, 0.f, 0.f, 0.f};
    const short* wrow = wb + (size_t)(16 * c + lr) * FDIM + lg * 8;
#pragma unroll
    for (int kk = 0; kk < 4; kk++) {
      bf16x8 B = *(const bf16x8*)(wrow + kk * 32);
      acc0 = __builtin_amdgcn_mfma_f32_16x16x32_bf16(A0[kk], B, acc0, 0, 0, 0);
      acc1 = __builtin_amdgcn_mfma_f32_16x16x32_bf16(A1[kk], B, acc1, 0, 0, 0);
    }
    int col = 16 * c + lr;
#pragma unroll
    for (int j = 0; j < 4; j++) {
      float m0 = gelu_fast(acc0[j]) * sv0[j];
      float m1 = gelu_fast(acc1[j]) * sv1[j];
      int row0 = rb + lg * 4 + j;
      mji8[(size_t)row0 * FDIM + col] =
          (unsigned char)(__builtin_amdgcn_cvt_pk_fp8_f32(m0, m0, 0, false) & 0xFF);
      mji8[(size_t)(row0 + 16) * FDIM + col] =
          (unsigned char)(__builtin_amdgcn_cvt_pk_fp8_f32(m1, m1, 0, false) & 0xFF);
    }
  }
}

// ---------------- edge reduce: 2 edges/wave, 2 subs per edge, packed f32x2 acc ----------------
__global__ __launch_bounds__(256) void k_edge(const unsigned char* __restrict__ mji8, const int* __restrict__ sn,
                                              const int* __restrict__ eoff, const int* __restrict__ ecnt,
                                              unsigned char* __restrict__ efeat8) {
  int wave = blockIdx.x * 4 + (threadIdx.x >> 6);
  int lane = threadIdx.x & 63;
  int half = lane >> 5;          // which edge of the 2
  int sub2 = (lane >> 4) & 1;    // which pair-interleave within the edge
  int c4 = lane & 15;
  int edge = wave * 2 + half;
  if (edge >= N_EDGESC) return;
  int beg = eoff[edge], cnt = ecnt[edge];
  f32x2 a0 = {0.f, 0.f}, a1 = {0.f, 0.f}, a2 = {0.f, 0.f}, a3 = {0.f, 0.f};
#pragma unroll 4
  for (int p = sub2; p < cnt; p += 2) {
    int node = sn[beg + p];
    uint2 u = ((const uint2*)(mji8 + (size_t)node * FDIM))[c4];
    a0 += __builtin_amdgcn_cvt_pk_f32_fp8(u.x, false);
    a1 += __builtin_amdgcn_cvt_pk_f32_fp8(u.x, true);
    a2 += __builtin_amdgcn_cvt_pk_f32_fp8(u.y, false);
    a3 += __builtin_amdgcn_cvt_pk_f32_fp8(u.y, true);
  }
  a0[0] += __shfl_xor(a0[0], 16, 64); a0[1] += __shfl_xor(a0[1], 16, 64);
  a1[0] += __shfl_xor(a1[0], 16, 64); a1[1] += __shfl_xor(a1[1], 16, 64);
  a2[0] += __shfl_xor(a2[0], 16, 64); a2[1] += __shfl_xor(a2[1], 16, 64);
  a3[0] += __shfl_xor(a3[0], 16, 64); a3[1] += __shfl_xor(a3[1], 16, 64);
  if (sub2 == 0) {
    float inv = 1.0f / fmaxf((float)cnt, 1.0f);
    uint2 o;
    o.x = (unsigned)__builtin_amdgcn_cvt_pk_fp8_f32(a0[0] * inv, a0[1] * inv, 0, false);
    o.x = (unsigned)__builtin_amdgcn_cvt_pk_fp8_f32(a1[0] * inv, a1[1] * inv, (int)o.x, true);
    o.y = (unsigned)__builtin_amdgcn_cvt_pk_fp8_f32(a2[0] * inv, a2[1] * inv, 0, false);
    o.y = (unsigned)__builtin_amdgcn_cvt_pk_fp8_f32(a3[0] * inv, a3[1] * inv, (int)o.y, true);
    ((uint2*)(efeat8 + (size_t)edge * FDIM))[c4] = o;
  }
}

// ---------------- node reduce: one node per 16-lane sub (4 nodes/wave) ----------------
__global__ __launch_bounds__(256) void k_node(const unsigned char* __restrict__ efeat8, const int* __restrict__ se,
                                              const int* __restrict__ noff, const int* __restrict__ ncnt,
                                              const float* __restrict__ recv, short* __restrict__ mi) {
  int wave = blockIdx.x * 4 + (threadIdx.x >> 6);
  int lane = threadIdx.x & 63;
  int sub = lane >> 4, c4 = lane & 15;
  int node = wave * 4 + sub;   // 25000 waves x 4 = 100000 exactly
  int beg = noff[node], cnt = ncnt[node];
  f32x2 a0 = {0.f, 0.f}, a1 = {0.f, 0.f}, a2 = {0.f, 0.f}, a3 = {0.f, 0.f};
#pragma unroll 4
  for (int p = 0; p < cnt; p++) {
    int e = se[beg + p];
    uint2 u = ((const uint2*)(efeat8 + (size_t)e * FDIM))[c4];
    a0 += __builtin_amdgcn_cvt_pk_f32_fp8(u.x, false);
    a1 += __builtin_amdgcn_cvt_pk_f32_fp8(u.x, true);
    a2 += __builtin_amdgcn_cvt_pk_f32_fp8(u.y, false);
    a3 += __builtin_amdgcn_cvt_pk_f32_fp8(u.y, true);
  }
  float s = recv[node] / fmaxf((float)cnt, 1.0f);
  u32x4 o;
  o[0] = pack2(a0[0] * s, a0[1] * s);
  o[1] = pack2(a1[0] * s, a1[1] * s);
  o[2] = pack2(a2[0] * s, a2[1] * s);
  o[3] = pack2(a3[0] * s, a3[1] * s);
  ((u32x4*)(mi + (size_t)node * FDIM))[c4] = o;
}

// ---------------- GEMM 2: out = gelu(x @ Wupd^T + b + m_i) -> f32, 32 rows/wave ----------------
__global__ __launch_bounds__(256) void k_gemm_upd(const short* __restrict__ xb, const short* __restrict__ wb,
                                                  const float* __restrict__ bias, const short* __restrict__ mi,
                                                  float* __restrict__ out) {
  int gw = (blockIdx.x * 256 + threadIdx.x) >> 6;
  int lane = threadIdx.x & 63;
  if (gw >= N_NODESC / 32) return;
  int rb = gw * 32;
  int lr = lane & 15, lg = lane >> 4;

  bf16x8 A0[4], A1[4];
  const short* xrow0 = xb + (size_t)(rb + lr) * FDIM + lg * 8;
  const short* xrow1 = xrow0 + 16 * FDIM;
#pragma unroll
  for (int kk = 0; kk < 4; kk++) {
    A0[kk] = *(const bf16x8*)(xrow0 + kk * 32);
    A1[kk] = *(const bf16x8*)(xrow1 + kk * 32);
  }

#pragma unroll
  for (int c = 0; c < 8; c++) {
    f32x4 acc0 = {0.f, 0.f, 0.f, 0.f}, acc1 = {0.f, 0.f, 0.f, 0.f};
    const short* wrow = wb + (size_t)(16 * c + lr) * FDIM + lg * 8;
#pragma unroll
    for (int kk = 0; kk < 4; kk++) {
      bf16x8 B = *(const bf16x8*)(wrow + kk * 32);
      acc0 = __builtin_amdgcn_mfma_f32_16x16x32_bf16(A0[kk], B, acc0, 0, 0, 0);
      acc1 = __builtin_amdgcn_mfma_f32_16x16x32_bf16(A1[kk], B, acc1, 0, 0, 0);
    }
    int col = 16 * c + lr;
    float bc = bias[col];
#pragma unroll
    for (int j = 0; j < 4; j++) {
      int row0 = rb + lg * 4 + j;
      float z0 = acc0[j] + bc + b2f(((const unsigned short*)mi)[(size_t)row0 * FDIM + col]);
      float z1 = acc1[j] + bc + b2f(((const unsigned short*)mi)[(size_t)(row0 + 16) * FDIM + col]);
      __builtin_nontemporal_store(gelu_fast(z0), &out[(size_t)row0 * FDIM + col]);
      __builtin_nontemporal_store(gelu_fast(z1), &out[(size_t)(row0 + 16) * FDIM + col]);
    }
  }
}

extern "C" void kernel_launch(void* const* d_in, const int* in_sizes, int n_in,
                              void* d_out, int out_size, void* d_ws, size_t ws_size,
                              hipStream_t stream) {
  const float* x = (const float*)d_in[0];
  const float* action = (const float*)d_in[1];
  const float* wmsg = (const float*)d_in[2];
  const float* wupd = (const float*)d_in[3];
  const float* bupd = (const float*)d_in[4];
  const int* pn = (const int*)d_in[5];
  const int* pe = (const int*)d_in[6];
  float* out = (float*)d_out;

  char* p = (char*)d_ws;
  auto alloc = [&](size_t bytes) -> char* {
    char* r = p;
    p += (bytes + 255) & ~(size_t)255;
    return r;
  };
  short* xb = (short*)alloc((size_t)N_NODESC * FDIM * 2);
  unsigned char* mji8 = (unsigned char*)alloc((size_t)N_NODESC * FDIM);
  short* mi = (short*)alloc((size_t)N_NODESC * FDIM * 2);   // also hosts buckE+buckN (consumed before k_node writes mi)
  unsigned char* efeat8 = (unsigned char*)alloc((size_t)N_EDGESC * FDIM);
  int* sn = (int*)alloc((size_t)N_PAIRSC * 4);
  int* se = (int*)alloc((size_t)N_PAIRSC * 4);
  short* wmsgb = (short*)alloc(FDIM * FDIM * 2);
  short* wupdb = (short*)alloc(FDIM * FDIM * 2);
  float* send = (float*)alloc(N_NODESC * 4);
  float* recv = (float*)alloc(N_NODESC * 4);
  int* ecnt = (int*)alloc(N_EDGESC * 4);
  int* eoff = (int*)alloc(N_EDGESC * 4);
  int* ncnt = (int*)alloc(N_NODESC * 4);
  int* noff = (int*)alloc(N_NODESC * 4);
  int* part = (int*)alloc((size_t)BH_BLOCKS * 2 * NB * 4);
  int* ebase = (int*)alloc((NB + 1) * 4);
  int* nbase = (int*)alloc((NB + 1) * 4);
  int* gcure = (int*)alloc(NB * 4);
  int* gcurn = (int*)alloc(NB * 4);

  unsigned* buckE = (unsigned*)mi;                      // 6.4 MB
  unsigned* buckN = buckE + (size_t)N_PAIRSC;           // 6.4 MB (fits mi's 25.6 MB region)

  k_prep<<<12500, 256, 0, stream>>>(x, action, wmsg, wupd, xb, wmsgb, wupdb, send, recv);
  k_bhist<<<BH_BLOCKS, 256, 0, stream>>>(pn, pe, part);
  k_bscan<<<1, 256, 0, stream>>>(part, ebase, nbase, gcure, gcurn);
  k_part<<<PA_NCH, 256, 0, stream>>>(pn, pe, gcure, gcurn, buckE, buckN);
  k_fine<<<2 * NB, 256, 0, stream>>>(buckE, buckN, ebase, nbase, ecnt, eoff, ncnt, noff, sn, se);
  k_gemm_msg<<<782, 256, 0, stream>>>(xb, wmsgb, send, mji8);
  k_edge<<<1250, 256, 0, stream>>>(mji8, sn, eoff, ecnt, efeat8);
  k_node<<<6250, 256, 0, stream>>>(efeat8, se, noff, ncnt, recv, mi);
  k_gemm_upd<<<782, 256, 0, stream>>>(xb, wupdb, bupd, mi, out);
}